// Round 6
// baseline (472.469 us; speedup 1.0000x reference)
//
#include <hip/hip_runtime.h>
#include <hip/hip_bf16.h>

// ---------------------------------------------------------------------------
// TransformerBlock: LN1 -> QKV GEMM -> causal flash attn -> out-proj(+x) -> h
//                   LN2 -> FFN1(+gelu) -> FFN2(+h) -> out
// GEMMs (R9): R3/R7's verified 2-buffer syncthreads-drained structure,
//   unchanged schedule, but 256x128 tile with 4 waves (256 thr): wave owns
//   64x128 (4m x 8n frags, 32 MFMA/K-step), LDS 48KB -> 3 blocks/CU.
//   Cuts staged bytes ~25% vs 128^2 (B-panel reuse doubles) while staying
//   in the verified occupancy regime. Zero-conflict XOR unit swizzle
//   (R5/R7-verified), XCD-chunked block swizzle.
//   NOTE: 512-thr/128KB-LDS 256^2 variants tried thrice (R4/R6/R8), all
//   regress to ~175us on 1-blk/CU exposure — do not revisit.
// Attn (R2): swapped QK^T, LDS-staged K/V, defer-max, cvt_pk P packing.
// ---------------------------------------------------------------------------

typedef float f32x4 __attribute__((ext_vector_type(4)));
typedef __bf16 bf16x8 __attribute__((ext_vector_type(8)));
typedef unsigned short u16;

#define MFMA16(a, b, c) __builtin_amdgcn_mfma_f32_16x16x32_bf16((a), (b), (c), 0, 0, 0)

#define GLL16(g, l)                                                            \
  __builtin_amdgcn_global_load_lds(                                            \
      (__attribute__((address_space(1))) void*)(g),                            \
      (__attribute__((address_space(3))) void*)(l), 16, 0, 0)

__device__ __forceinline__ u16 f2bf(float f) {
  union { float f; unsigned int u; } x; x.f = f;
  unsigned int r = x.u + 0x7fffu + ((x.u >> 16) & 1u);
  return (u16)(r >> 16);
}

// ---------------- LayerNorm: fp32 in -> bf16 out, one row per block ---------
__global__ __launch_bounds__(256) void ln_kernel(
    const float* __restrict__ x, const float* __restrict__ g,
    const float* __restrict__ b, u16* __restrict__ y)
{
  int row = blockIdx.x;
  int t = threadIdx.x;
  const float4* xr = (const float4*)(x + (size_t)row * 1024);
  float4 v = xr[t];
  float s  = v.x + v.y + v.z + v.w;
  float ss = v.x*v.x + v.y*v.y + v.z*v.z + v.w*v.w;
#pragma unroll
  for (int off = 1; off < 64; off <<= 1) {
    s  += __shfl_xor(s, off);
    ss += __shfl_xor(ss, off);
  }
  __shared__ float red[8];
  int w = t >> 6;
  if ((t & 63) == 0) { red[w*2] = s; red[w*2+1] = ss; }
  __syncthreads();
  s  = red[0] + red[2] + red[4] + red[6];
  ss = red[1] + red[3] + red[5] + red[7];
  float mu  = s * (1.0f / 1024.0f);
  float var = ss * (1.0f / 1024.0f) - mu * mu;
  float rs  = rsqrtf(var + 1e-5f);
  float4 gg = ((const float4*)g)[t];
  float4 bb = ((const float4*)b)[t];
  ushort4 o;
  o.x = f2bf((v.x - mu) * rs * gg.x + bb.x);
  o.y = f2bf((v.y - mu) * rs * gg.y + bb.y);
  o.z = f2bf((v.z - mu) * rs * gg.z + bb.z);
  o.w = f2bf((v.w - mu) * rs * gg.w + bb.w);
  ((ushort4*)y)[(size_t)row * 256 + t] = o;
}

// ------------- weight convert+transpose: W[K][N] fp32 -> Wt[N][K] bf16 ------
__global__ __launch_bounds__(256) void wt_kernel(
    const float* __restrict__ W, u16* __restrict__ Wt, int K, int N)
{
  __shared__ u16 tile[32][33];
  int n0 = blockIdx.x * 32, k0 = blockIdx.y * 32;
  int t = threadIdx.x, tr = t >> 5, tc = t & 31;
#pragma unroll
  for (int i = 0; i < 4; ++i) {
    int k = k0 + tr + i * 8;
    tile[tc][tr + i * 8] = f2bf(W[(size_t)k * N + n0 + tc]);
  }
  __syncthreads();
#pragma unroll
  for (int i = 0; i < 4; ++i) {
    int n = n0 + tr + i * 8;
    Wt[(size_t)n * K + k0 + tc] = tile[tr + i * 8][tc];
  }
}

// ------------- V transpose: qkv[b,l,2,h,d] bf16 -> Vt[b,h,d,l] bf16 ---------
__global__ __launch_bounds__(256) void vt_kernel(
    const u16* __restrict__ qkv, u16* __restrict__ vt)
{
  __shared__ u16 tile[64][65];
  int bid = blockIdx.x;
  int lt = bid & 31, h = (bid >> 5) & 15, b = bid >> 9;
  int t = threadIdx.x;
  int tr = t >> 4, tc4 = (t & 15) * 4;
  const u16* src = qkv + ((size_t)(b * 2048 + lt * 64)) * 3072 + 2048 + h * 64;
#pragma unroll
  for (int i = 0; i < 4; ++i) {
    int ll = tr + i * 16;
    ushort4 v = *(const ushort4*)(src + (size_t)ll * 3072 + tc4);
    tile[ll][tc4] = v.x; tile[ll][tc4+1] = v.y; tile[ll][tc4+2] = v.z; tile[ll][tc4+3] = v.w;
  }
  __syncthreads();
  u16* dst = vt + ((size_t)(b * 16 + h) * 64) * 2048 + lt * 64;
#pragma unroll
  for (int i = 0; i < 4; ++i) {
    int d = tr + i * 16;
    ushort4 o;
    o.x = tile[tc4][d]; o.y = tile[tc4+1][d]; o.z = tile[tc4+2][d]; o.w = tile[tc4+3][d];
    *(ushort4*)(dst + (size_t)d * 2048 + tc4) = o;
  }
}

// ------------------------------- GEMM ---------------------------------------
// C[M][N] = A[M][K](bf16) * Bt[N][K](bf16)^T + bias; optional gelu/residual.
// Tile 256(M) x 128(N), 4 waves stacked in M (wave tile 64x128), BK=32.
// 2-phase double-buffered: stage tile kt+1 into buf^1 while computing kt;
// __syncthreads() at step end drains vmcnt (m97 structure, verified R3/R7).
// LDS swizzle (zero-conflict, verified R5/R7): row r (64B = 4x16B units),
// unit j holds global unit j ^ ((r>>1)&3). Staging pre-swizzles the GLOBAL
// source (global_load_lds writes linearly); frag reads XOR the unit index;
// both collapse to per-thread constants.
template<int GELU, int HAS_RES, int OUT_BF16>
__global__ __launch_bounds__(256, 2) void gemm_kernel(
    const u16* __restrict__ A, const u16* __restrict__ Bt,
    const float* __restrict__ bias, const float* __restrict__ res,
    void* __restrict__ Cout, int M, int N, int K)
{
  __shared__ u16 lA[2][256 * 32];   // 16KB/buf
  __shared__ u16 lB[2][128 * 32];   // 8KB/buf   -> 48KB total, 3 blk/CU
  const int nbn = N >> 7;
  // XCD-chunked bijective swizzle (all grids here are multiples of 8)
  int nwg = gridDim.x;
  int wg = blockIdx.x;
  if ((nwg & 7) == 0) wg = (wg & 7) * (nwg >> 3) + (wg >> 3);
  int bm = wg / nbn, bn = wg % nbn;
  int tid = threadIdx.x;
  int w = tid >> 6, l = tid & 63;
  int lh = l & 15, lg = l >> 4;
  const size_t Kb = (size_t)K * 2;
  const char* Ab = (const char*)A + (size_t)(bm * 256) * Kb;
  const char* Bb = (const char*)Bt + (size_t)(bn * 128) * Kb;

  // staging: A = 1024 16B units/step (256 rows x 4), B = 512 units.
  // thread handles A units {tid + 256j, j=0..3}, B units {tid + 256j, j=0..1}.
  // unit c: row = c>>2; for c = tid+256j both (c&3) and ((c>>3)&3) are
  // j-invariant -> one per-thread source swizzle constant.
  const int swst = ((tid ^ (tid >> 3)) & 3) << 4;
  const size_t stA = (size_t)(tid >> 2) * Kb + swst;

#define GSTAGE(sel, kt)                                                        \
  do {                                                                         \
    GLL16(Ab + stA + (size_t)(kt) * 64,            (char*)lA[sel] + tid * 16); \
    GLL16(Ab + stA + 64 * Kb + (size_t)(kt) * 64,                              \
          (char*)lA[sel] + tid * 16 + 4096);                                   \
    GLL16(Ab + stA + 128 * Kb + (size_t)(kt) * 64,                             \
          (char*)lA[sel] + tid * 16 + 8192);                                   \
    GLL16(Ab + stA + 192 * Kb + (size_t)(kt) * 64,                             \
          (char*)lA[sel] + tid * 16 + 12288);                                  \
    GLL16(Bb + stA + (size_t)(kt) * 64,            (char*)lB[sel] + tid * 16); \
    GLL16(Bb + stA + 64 * Kb + (size_t)(kt) * 64,                              \
          (char*)lB[sel] + tid * 16 + 4096);                                   \
  } while (0)

  // frag-read swizzle: row = (mult of 16) + lh -> ((row>>1)&3) == ((lh>>1)&3)
  const int swo = ((lg ^ (lh >> 1)) & 3) << 4;
  const int offA = (w * 64 + lh) * 64 + swo;    // + m*1024 per m-frag (bytes)
  const int offB = lh * 64 + swo;               // + n*1024 per n-frag (bytes)

  f32x4 acc[4][8] = {};
  const int nkt = K >> 5;
  GSTAGE(0, 0);
  __syncthreads();
  int cur = 0;
#pragma unroll 1
  for (int kt = 0; kt < nkt; ++kt) {
    if (kt + 1 < nkt) GSTAGE(cur ^ 1, kt + 1);   // async, lands under compute
    const char* bufA = (const char*)lA[cur];
    const char* bufB = (const char*)lB[cur];
    bf16x8 af[4], bfr[8];
#pragma unroll
    for (int m = 0; m < 4; ++m)
      af[m] = *(const bf16x8*)(bufA + offA + m * 1024);
#pragma unroll
    for (int n = 0; n < 8; ++n)
      bfr[n] = *(const bf16x8*)(bufB + offB + n * 1024);
#pragma unroll
    for (int m = 0; m < 4; ++m)
#pragma unroll
      for (int n = 0; n < 8; ++n)
        acc[m][n] = MFMA16(af[m], bfr[n], acc[m][n]);
    __syncthreads();   // drains vmcnt(0): buf^1 staged; all reads of cur done
    cur ^= 1;
  }
#undef GSTAGE

#pragma unroll
  for (int m = 0; m < 4; ++m) {
    int row0 = bm * 256 + w * 64 + m * 16 + lg * 4;
#pragma unroll
    for (int n = 0; n < 8; ++n) {
      int col = bn * 128 + n * 16 + lh;
      float bv = bias[col];
#pragma unroll
      for (int r = 0; r < 4; ++r) {
        int row = row0 + r;
        float v = acc[m][n][r] + bv;
        if (GELU) v = 0.5f * v * (1.0f + erff(v * 0.70710678118f));
        if (HAS_RES) v += res[(size_t)row * N + col];
        if (OUT_BF16) ((u16*)Cout)[(size_t)row * N + col] = f2bf(v);
        else ((float*)Cout)[(size_t)row * N + col] = v;
      }
    }
  }
  (void)M;
}

// --------------------------- causal flash attention -------------------------
// grid 1024: bid -> (pi = bid>>6, bh = bid&63) so all 16 pi-blocks of one
// (b,h) land on XCD bh%8 (L2 locality). Block = 4 waves; wave owns 16 q rows;
// q-tiles {pi, 31-pi} -> 33 KV-tile iters per block (balanced).
// K/V tiles staged via global_load_lds into double-buffered XOR-swizzled LDS.
// Swapped QK^T: S^T[k][q] = mfma(K, Q): lane holds 16 k's for q=lane&15 ->
// softmax reductions = local ops + 2 shuffles. PV: O^T = mfma(V^T, P^T).
__global__ __launch_bounds__(256, 4) void attn_kernel(
    const u16* __restrict__ qkv, const u16* __restrict__ vt,
    u16* __restrict__ out)
{
  __shared__ u16 Ks[2][4096];   // [buf][64 k][64 d] swizzled, 8KB each
  __shared__ u16 Vs[2][4096];   // [buf][64 d][64 k] swizzled
  __shared__ u16 Ps[4][1024];   // per-wave P [16 q][64 k] swizzled, 2KB each

  const float C = 0.18033688011f;  // 0.125 * log2(e)

  int bid = blockIdx.x;
  int pi = bid >> 6, bh = bid & 63;
  int b = bh >> 4, h = bh & 15;
  int tid = threadIdx.x;
  int w = tid >> 6, l = tid & 63;
  int lh = l & 15, lg = l >> 4;
  int lh7 = lh & 7;

  const char* kg = (const char*)qkv + (size_t)(b * 2048) * 6144 + 2048 + h * 128;
  const char* vg = (const char*)vt + (size_t)((b * 16 + h) * 64) * 4096;
  char* pbw = (char*)Ps[w] + lh * 128;

#pragma unroll 1
  for (int half = 0; half < 2; ++half) {
    int qb = half ? (31 - pi) : pi;
    int q0 = qb * 64 + w * 16;
    const u16* qbase = qkv + ((size_t)(b * 2048) + q0) * 3072 + h * 64;
    bf16x8 aq0 = *(const bf16x8*)(qbase + (size_t)lh * 3072 + lg * 8);
    bf16x8 aq1 = *(const bf16x8*)(qbase + (size_t)lh * 3072 + 32 + lg * 8);

    f32x4 o[4] = {};
    float m = -1e30f;
    float lsum = 0.f;
    int nt = qb + 1;

    __syncthreads();   // protect buf0 from previous half's readers
    // prologue stage tile 0 -> buf 0 (K: 512 16B units, V: 512)
#pragma unroll
    for (int i = 0; i < 2; ++i) {
      int u = tid + i * 256;
      int row = u >> 3, uc = u & 7, sw = uc ^ (row & 7);
      GLL16(kg + (size_t)row * 6144 + sw * 16,
            (char*)Ks[0] + (size_t)(i * 256 + w * 64) * 16);
      GLL16(vg + (size_t)row * 4096 + sw * 16,
            (char*)Vs[0] + (size_t)(i * 256 + w * 64) * 16);
    }

#pragma unroll 1
    for (int kt = 0; kt < nt; ++kt) {
      int cur = kt & 1;
      __syncthreads();   // stage for kt complete; prev buf free
      if (kt + 1 < nt) {
        int nxt = cur ^ 1;
        size_t kofs = (size_t)(kt + 1) * 64;
#pragma unroll
        for (int i = 0; i < 2; ++i) {
          int u = tid + i * 256;
          int row = u >> 3, uc = u & 7, sw = uc ^ (row & 7);
          GLL16(kg + (kofs + row) * 6144 + sw * 16,
                (char*)Ks[nxt] + (size_t)(i * 256 + w * 64) * 16);
          GLL16(vg + (size_t)row * 4096 + kofs * 2 + sw * 16,
                (char*)Vs[nxt] + (size_t)(i * 256 + w * 64) * 16);
        }
      }
      // ---- QK^T: S^T[k][q], lane: q=lh, k = kb*16+lg*4+r ----
      const char* kbuf = (const char*)Ks[cur];
      f32x4 s[4];
#pragma unroll
      for (int kb = 0; kb < 4; ++kb) {
        int row = kb * 16 + lh;
        const char* rp = kbuf + row * 128;
        bf16x8 a0 = *(const bf16x8*)(rp + ((lg ^ lh7) << 4));
        bf16x8 a1 = *(const bf16x8*)(rp + (((4 + lg) ^ lh7) << 4));
        f32x4 z = {0.f, 0.f, 0.f, 0.f};
        z = MFMA16(a0, aq0, z);
        z = MFMA16(a1, aq1, z);
        s[kb] = z;
      }
      // ---- mask (diagonal tile only; wave-uniform branch) ----
      if (kt == qb) {
        int qin = w * 16 + lh;
#pragma unroll
        for (int kb = 0; kb < 4; ++kb)
#pragma unroll
          for (int r = 0; r < 4; ++r)
            if (kb * 16 + lg * 4 + r > qin) s[kb][r] = -1e30f;
      }
      // ---- row max (local + 2 shuffles) ----
      float tm = fmaxf(fmaxf(s[0][0], s[0][1]), fmaxf(s[0][2], s[0][3]));
#pragma unroll
      for (int kb = 1; kb < 4; ++kb)
        tm = fmaxf(tm, fmaxf(fmaxf(s[kb][0], s[kb][1]), fmaxf(s[kb][2], s[kb][3])));
      tm = fmaxf(tm, __shfl_xor(tm, 16));
      tm = fmaxf(tm, __shfl_xor(tm, 32));
      // ---- defer-max rescale (THR = 8 scaled = 64 unscaled) ----
      if (__any(tm > m + 64.0f)) {
        float nm = fmaxf(m, tm);
        float f = __builtin_amdgcn_exp2f((m - nm) * C);
        m = nm; lsum *= f;
#pragma unroll
        for (int db = 0; db < 4; ++db)
#pragma unroll
          for (int r = 0; r < 4; ++r) o[db][r] *= f;
      }
      // ---- exp (fused scale via exp2) + row sum ----
      float mc = m * C;
      float ps = 0.f;
#pragma unroll
      for (int kb = 0; kb < 4; ++kb)
#pragma unroll
        for (int r = 0; r < 4; ++r) {
          float p = __builtin_amdgcn_exp2f(fmaf(s[kb][r], C, -mc));
          s[kb][r] = p;
          ps += p;
        }
      ps += __shfl_xor(ps, 16);
      ps += __shfl_xor(ps, 32);
      lsum += ps;
      // ---- pack P -> LDS (cvt_pk pairs, b64 writes, 16B-unit swizzle) ----
#pragma unroll
      for (int kb = 0; kb < 4; ++kb) {
        unsigned lo, hi;
        asm("v_cvt_pk_bf16_f32 %0, %1, %2" : "=v"(lo) : "v"(s[kb][0]), "v"(s[kb][1]));
        asm("v_cvt_pk_bf16_f32 %0, %1, %2" : "=v"(hi) : "v"(s[kb][2]), "v"(s[kb][3]));
        int unit = kb * 2 + (lg >> 1);
        uint2 val; val.x = lo; val.y = hi;
        *(uint2*)(pbw + ((unit ^ lh7) << 4) + ((lg & 1) << 3)) = val;
      }
      // ---- PV: O^T += mfma(V^T frag, P^T frag) ----
      bf16x8 pa0 = *(const bf16x8*)(pbw + ((lg ^ lh7) << 4));
      bf16x8 pa1 = *(const bf16x8*)(pbw + (((4 + lg) ^ lh7) << 4));
      const char* vbuf = (const char*)Vs[cur];
#pragma unroll
      for (int db = 0; db < 4; ++db) {
        int row = db * 16 + lh;
        const char* rp = vbuf + row * 128;
        bf16x8 v0 = *(const bf16x8*)(rp + ((lg ^ lh7) << 4));
        bf16x8 v1 = *(const bf16x8*)(rp + (((4 + lg) ^ lh7) << 4));
        o[db] = MFMA16(v0, pa0, o[db]);
        o[db] = MFMA16(v1, pa1, o[db]);
      }
    }
    // ---- epilogue: lane owns q = q0+lh, d = db*16+lg*4+r ----
    float rinv = 1.0f / lsum;
    u16* ob = out + ((size_t)(b * 2048) + q0 + lh) * 1024 + h * 64;
#pragma unroll
    for (int db = 0; db < 4; ++db) {
      ushort4 pk;
      pk.x = f2bf(o[db][0] * rinv);
      pk.y = f2bf(o[db][1] * rinv);
      pk.z = f2bf(o[db][2] * rinv);
      pk.w = f2bf(o[db][3] * rinv);
      *(ushort4*)(ob + db * 16 + lg * 4) = pk;
    }
  }
}

// ---------------------------------------------------------------------------
extern "C" void kernel_launch(void* const* d_in, const int* in_sizes, int n_in,
                              void* d_out, int out_size, void* d_ws, size_t ws_size,
                              hipStream_t stream) {
  const float* x     = (const float*)d_in[0];
  const float* ln1_g = (const float*)d_in[1];
  const float* ln1_b = (const float*)d_in[2];
  const float* w_qkv = (const float*)d_in[3];
  const float* b_qkv = (const float*)d_in[4];
  const float* w_out = (const float*)d_in[5];
  const float* b_out = (const float*)d_in[6];
  const float* ln2_g = (const float*)d_in[7];
  const float* ln2_b = (const float*)d_in[8];
  const float* w1    = (const float*)d_in[9];
  const float* b1    = (const float*)d_in[10];
  const float* w2    = (const float*)d_in[11];
  const float* b2    = (const float*)d_in[12];

  char* ws = (char*)d_ws;
  // liveness-aliased layout, 142.6 MB total
  u16* wqkvT = (u16*)(ws + 0);          // 6.29 MB
  u16* woutT = (u16*)(ws + 6291456);    // 2.10 MB
  u16* w1T   = (u16*)(ws + 8388608);    // 8.39 MB
  u16* w2T   = (u16*)(ws + 16777216);   // 8.39 MB
  u16* qkv   = (u16*)(ws + 25165824);   // 50.3 MB  [b,l,3,h,d]
  u16* ffn1  = (u16*)(ws + 25165824);   // 67.1 MB  (aliases qkv+vt, both dead)
  u16* vtb   = (u16*)(ws + 75497472);   // 16.8 MB  [b,h,d,l]
  u16* lnb   = (u16*)(ws + 92274688);   // 16.8 MB  (ln1 out / attn out / ln2 out)
  u16* attn  = lnb;
  float* h   = (float*)(ws + 125829120);// 33.6 MB

  wt_kernel<<<dim3(96, 32), 256, 0, stream>>>(w_qkv, wqkvT, 1024, 3072);
  wt_kernel<<<dim3(32, 32), 256, 0, stream>>>(w_out, woutT, 1024, 1024);
  wt_kernel<<<dim3(128, 32), 256, 0, stream>>>(w1, w1T, 1024, 4096);
  wt_kernel<<<dim3(32, 128), 256, 0, stream>>>(w2, w2T, 4096, 1024);

  ln_kernel<<<8192, 256, 0, stream>>>(x, ln1_g, ln1_b, lnb);
  // QKV: M=8192 N=3072 K=1024, 256x128 tile -> 32x24 = 768 wg
  gemm_kernel<0, 0, 1><<<768, 256, 0, stream>>>(lnb, wqkvT, b_qkv, nullptr, qkv, 8192, 3072, 1024);
  vt_kernel<<<2048, 256, 0, stream>>>(qkv, vtb);
  attn_kernel<<<1024, 256, 0, stream>>>(qkv, vtb, attn);
  // out-proj: M=8192 N=1024 K=1024 -> 32x8 = 256 wg
  gemm_kernel<0, 1, 0><<<256, 256, 0, stream>>>(attn, woutT, b_out, x, h, 8192, 1024, 1024);
  ln_kernel<<<8192, 256, 0, stream>>>(h, ln2_g, ln2_b, lnb);
  // FFN1: M=8192 N=4096 K=1024 -> 32x32 = 1024 wg
  gemm_kernel<1, 0, 1><<<1024, 256, 0, stream>>>(lnb, w1T, b1, nullptr, ffn1, 8192, 4096, 1024);
  // FFN2: M=8192 N=1024 K=4096 -> 32x8 = 256 wg
  gemm_kernel<0, 1, 0><<<256, 256, 0, stream>>>(ffn1, w2T, b2, h, (float*)d_out, 8192, 1024, 4096);
}

// Round 7
// 409.276 us; speedup vs baseline: 1.1544x; 1.1544x over previous
//
#include <hip/hip_runtime.h>
#include <hip/hip_bf16.h>

// ---------------------------------------------------------------------------
// TransformerBlock: LN1 -> QKV GEMM -> causal flash attn -> out-proj(+x) -> h
//                   LN2 -> FFN1(+gelu) -> FFN2(+h) -> out
// GEMMs (R10):
//  * QKV/FFN1: NEW gemm256_kernel — 256x256, BK=64, 8 waves, 2 LDS dbufs,
//    counted vmcnt(8) (T4): stage tile t+2 into buf[cur] after a
//    mid-iteration lgkmcnt(0)+s_barrier frees it; end-of-iter waits only
//    vmcnt(8) so t+2's loads stay in flight a FULL iteration. Raw s_barrier
//    (never __syncthreads = forced drain). Conflict-0 unit^(row&7) swizzle
//    (byte-identical to the attn kernel's verified staging).
//  * out-proj/FFN2 (N=1024): R7's verified 128x128 2-buf kernel unchanged.
// Attn (R2): swapped QK^T, LDS-staged K/V, defer-max, cvt_pk P packing.
// ---------------------------------------------------------------------------

typedef float f32x4 __attribute__((ext_vector_type(4)));
typedef __bf16 bf16x8 __attribute__((ext_vector_type(8)));
typedef unsigned short u16;

#define MFMA16(a, b, c) __builtin_amdgcn_mfma_f32_16x16x32_bf16((a), (b), (c), 0, 0, 0)

#define GLL16(g, l)                                                            \
  __builtin_amdgcn_global_load_lds(                                            \
      (__attribute__((address_space(1))) void*)(g),                            \
      (__attribute__((address_space(3))) void*)(l), 16, 0, 0)

#define BAR()                                                                  \
  do {                                                                         \
    __builtin_amdgcn_sched_barrier(0);                                         \
    __builtin_amdgcn_s_barrier();                                              \
    asm volatile("" ::: "memory");                                             \
    __builtin_amdgcn_sched_barrier(0);                                         \
  } while (0)

__device__ __forceinline__ u16 f2bf(float f) {
  union { float f; unsigned int u; } x; x.f = f;
  unsigned int r = x.u + 0x7fffu + ((x.u >> 16) & 1u);
  return (u16)(r >> 16);
}

// ---------------- LayerNorm: fp32 in -> bf16 out, one row per block ---------
__global__ __launch_bounds__(256) void ln_kernel(
    const float* __restrict__ x, const float* __restrict__ g,
    const float* __restrict__ b, u16* __restrict__ y)
{
  int row = blockIdx.x;
  int t = threadIdx.x;
  const float4* xr = (const float4*)(x + (size_t)row * 1024);
  float4 v = xr[t];
  float s  = v.x + v.y + v.z + v.w;
  float ss = v.x*v.x + v.y*v.y + v.z*v.z + v.w*v.w;
#pragma unroll
  for (int off = 1; off < 64; off <<= 1) {
    s  += __shfl_xor(s, off);
    ss += __shfl_xor(ss, off);
  }
  __shared__ float red[8];
  int w = t >> 6;
  if ((t & 63) == 0) { red[w*2] = s; red[w*2+1] = ss; }
  __syncthreads();
  s  = red[0] + red[2] + red[4] + red[6];
  ss = red[1] + red[3] + red[5] + red[7];
  float mu  = s * (1.0f / 1024.0f);
  float var = ss * (1.0f / 1024.0f) - mu * mu;
  float rs  = rsqrtf(var + 1e-5f);
  float4 gg = ((const float4*)g)[t];
  float4 bb = ((const float4*)b)[t];
  ushort4 o;
  o.x = f2bf((v.x - mu) * rs * gg.x + bb.x);
  o.y = f2bf((v.y - mu) * rs * gg.y + bb.y);
  o.z = f2bf((v.z - mu) * rs * gg.z + bb.z);
  o.w = f2bf((v.w - mu) * rs * gg.w + bb.w);
  ((ushort4*)y)[(size_t)row * 256 + t] = o;
}

// ------------- weight convert+transpose: W[K][N] fp32 -> Wt[N][K] bf16 ------
__global__ __launch_bounds__(256) void wt_kernel(
    const float* __restrict__ W, u16* __restrict__ Wt, int K, int N)
{
  __shared__ u16 tile[32][33];
  int n0 = blockIdx.x * 32, k0 = blockIdx.y * 32;
  int t = threadIdx.x, tr = t >> 5, tc = t & 31;
#pragma unroll
  for (int i = 0; i < 4; ++i) {
    int k = k0 + tr + i * 8;
    tile[tc][tr + i * 8] = f2bf(W[(size_t)k * N + n0 + tc]);
  }
  __syncthreads();
#pragma unroll
  for (int i = 0; i < 4; ++i) {
    int n = n0 + tr + i * 8;
    Wt[(size_t)n * K + k0 + tc] = tile[tr + i * 8][tc];
  }
}

// ------------- V transpose: qkv[b,l,2,h,d] bf16 -> Vt[b,h,d,l] bf16 ---------
__global__ __launch_bounds__(256) void vt_kernel(
    const u16* __restrict__ qkv, u16* __restrict__ vt)
{
  __shared__ u16 tile[64][65];
  int bid = blockIdx.x;
  int lt = bid & 31, h = (bid >> 5) & 15, b = bid >> 9;
  int t = threadIdx.x;
  int tr = t >> 4, tc4 = (t & 15) * 4;
  const u16* src = qkv + ((size_t)(b * 2048 + lt * 64)) * 3072 + 2048 + h * 64;
#pragma unroll
  for (int i = 0; i < 4; ++i) {
    int ll = tr + i * 16;
    ushort4 v = *(const ushort4*)(src + (size_t)ll * 3072 + tc4);
    tile[ll][tc4] = v.x; tile[ll][tc4+1] = v.y; tile[ll][tc4+2] = v.z; tile[ll][tc4+3] = v.w;
  }
  __syncthreads();
  u16* dst = vt + ((size_t)(b * 16 + h) * 64) * 2048 + lt * 64;
#pragma unroll
  for (int i = 0; i < 4; ++i) {
    int d = tr + i * 16;
    ushort4 o;
    o.x = tile[tc4][d]; o.y = tile[tc4+1][d]; o.z = tile[tc4+2][d]; o.w = tile[tc4+3][d];
    *(ushort4*)(dst + (size_t)d * 2048 + tc4) = o;
  }
}

// ------------------ GEMM 256x256 BK=64, counted vmcnt (T4) ------------------
// C[M][N] = A[M][K](bf16) * Bt[N][K](bf16)^T + bias; optional gelu.
// Iter t (dbuf cur = t&1):
//   ds_read all 24 frags of tile t (compiler inserts lgkm waits for MFMA)
//   MFMA ks0 cluster (32)
//   lgkmcnt(0); BARRIER#1           -> buf[cur] free for all waves
//   STAGE(t+2 -> buf[cur])          -> 8 loads, land during NEXT iteration
//   MFMA ks1 cluster (32, reg-only)
//   vmcnt(8) [vmcnt(0) at t=nkt-2]; BARRIER#2 -> tile t+1 resident
// Loads thus always have >= 1 full iteration in flight; never drained to 0
// in steady state (R8's failure was drain-to-0 per tile).
// LDS layout per buf: A[256][64] (32KB) then B[256][64]; row = 8 16B units,
// phys unit = logical unit ^ (row&7) — attn-verified conflict-free pattern;
// staging pre-swizzles the GLOBAL source (global_load_lds writes linearly).
template<int GELU, int OUT_BF16>
__global__ __launch_bounds__(512, 2) void gemm256_kernel(
    const u16* __restrict__ A, const u16* __restrict__ Bt,
    const float* __restrict__ bias, void* __restrict__ Cout,
    int M, int N, int K)
{
  __shared__ u16 lds[2][512 * 64];   // 64KB per buf (A 32KB + B 32KB)
  const int nbn = N >> 8;
  int nwg = gridDim.x, wg = blockIdx.x;
  if ((nwg & 7) == 0) wg = (wg & 7) * (nwg >> 3) + (wg >> 3);
  const int bm = wg / nbn, bn = wg % nbn;
  const int tid = threadIdx.x;
  const int w = tid >> 6, l = tid & 63;
  const int lh = l & 15, lg = l >> 4;
  const int wr = w >> 2, wc = w & 3;          // 2(M) x 4(N) wave grid
  const size_t Kb = (size_t)K * 2;
  const char* Ab = (const char*)A + (size_t)(bm * 256) * Kb;
  const char* Bb = (const char*)Bt + (size_t)(bn * 256) * Kb;

  // staging: 2048 16B units per operand; thread stages units tid + 512k.
  // unit u: row = u>>3 = (tid>>3)+64k, phys col unit = tid&7,
  // logical col unit = (tid&7) ^ (row&7) = (tid&7) ^ ((tid>>3)&7) (k-inv).
  const int jsrc = (((tid & 7) ^ ((tid >> 3) & 7)) << 4);
  const size_t srow = (size_t)(tid >> 3) * Kb;

#define GS1(gb, db, kt)                                                        \
  do {                                                                         \
    const char* s_ = (gb) + srow + (size_t)(kt) * 128 + jsrc;                  \
    char* d_ = (db) + tid * 16;                                                \
    GLL16(s_, d_);                   GLL16(s_ + 64 * Kb, d_ + 8192);           \
    GLL16(s_ + 128 * Kb, d_ + 16384); GLL16(s_ + 192 * Kb, d_ + 24576);        \
  } while (0)
#define GSTAGE(sel, kt)                                                        \
  do { GS1(Ab, (char*)lds[sel], kt); GS1(Bb, (char*)lds[sel] + 32768, kt); } while (0)

  // frag reads: row = base16 + lh -> row&7 == lh&7; ks0 unit = lg^(lh&7),
  // ks1 unit = (4+lg)^(lh&7) — same constants as the attn kernel.
  const int x0 = ((lg ^ (lh & 7)) & 7) << 4;
  const int x1 = (((4 + lg) ^ (lh & 7)) & 7) << 4;
  const int offA = (wr * 128 + lh) * 128;           // + m*2048 + x0/x1
  const int offB = 32768 + (wc * 64 + lh) * 128;    // + n*2048 + x0/x1

  f32x4 acc[8][4] = {};
  const int nkt = K >> 6;
  GSTAGE(0, 0);
  GSTAGE(1, 1);
  asm volatile("s_waitcnt vmcnt(8)" ::: "memory");   // tile 0 resident
  BAR();

#pragma unroll 1
  for (int t = 0; t < nkt; ++t) {
    const int cur = t & 1;
    const char* buf = (const char*)lds[cur];
    bf16x8 a0[8], b0[4], a1[8], b1[4];
#pragma unroll
    for (int m = 0; m < 8; ++m) {
      a0[m] = *(const bf16x8*)(buf + offA + m * 2048 + x0);
      a1[m] = *(const bf16x8*)(buf + offA + m * 2048 + x1);
    }
#pragma unroll
    for (int n = 0; n < 4; ++n) {
      b0[n] = *(const bf16x8*)(buf + offB + n * 2048 + x0);
      b1[n] = *(const bf16x8*)(buf + offB + n * 2048 + x1);
    }
    // ks0 cluster (compiler inserts the lgkm waits it needs)
    __builtin_amdgcn_s_setprio(1);
#pragma unroll
    for (int m = 0; m < 8; ++m)
#pragma unroll
      for (int n = 0; n < 4; ++n)
        acc[m][n] = MFMA16(a0[m], b0[n], acc[m][n]);
    __builtin_amdgcn_s_setprio(0);
    // all 24 reads retired -> buf[cur] reusable after barrier
    asm volatile("s_waitcnt lgkmcnt(0)" ::: "memory");
    BAR();
    if (t + 2 < nkt) GSTAGE(cur, t + 2);   // in flight through next iteration
    // ks1 cluster: operands already in registers, no LDS dependency
    __builtin_amdgcn_s_setprio(1);
#pragma unroll
    for (int m = 0; m < 8; ++m)
#pragma unroll
      for (int n = 0; n < 4; ++n)
        acc[m][n] = MFMA16(a1[m], b1[n], acc[m][n]);
    __builtin_amdgcn_s_setprio(0);
    if (t + 1 < nkt) {
      __builtin_amdgcn_sched_barrier(0);
      if (t + 2 < nkt) asm volatile("s_waitcnt vmcnt(8)" ::: "memory");
      else             asm volatile("s_waitcnt vmcnt(0)" ::: "memory");
      BAR();                               // tile t+1 resident for all waves
    }
  }
#undef GSTAGE
#undef GS1

#pragma unroll
  for (int m = 0; m < 8; ++m) {
    int row0 = bm * 256 + wr * 128 + m * 16 + lg * 4;
#pragma unroll
    for (int n = 0; n < 4; ++n) {
      int col = bn * 256 + wc * 64 + n * 16 + lh;
      float bv = bias[col];
#pragma unroll
      for (int r = 0; r < 4; ++r) {
        int row = row0 + r;
        float v = acc[m][n][r] + bv;
        if (GELU) v = 0.5f * v * (1.0f + erff(v * 0.70710678118f));
        if (OUT_BF16) ((u16*)Cout)[(size_t)row * N + col] = f2bf(v);
        else ((float*)Cout)[(size_t)row * N + col] = v;
      }
    }
  }
  (void)M;
}

// ------------------------- GEMM 128x128 (R7, verified) ----------------------
template<int GELU, int HAS_RES, int OUT_BF16>
__global__ __launch_bounds__(256, 2) void gemm_kernel(
    const u16* __restrict__ A, const u16* __restrict__ Bt,
    const float* __restrict__ bias, const float* __restrict__ res,
    void* __restrict__ Cout, int M, int N, int K)
{
  __shared__ u16 lA[2][128 * 32];
  __shared__ u16 lB[2][128 * 32];
  const int nbn = N >> 7;
  int nwg = gridDim.x;
  int wg = blockIdx.x;
  if ((nwg & 7) == 0) wg = (wg & 7) * (nwg >> 3) + (wg >> 3);
  int bm = wg / nbn, bn = wg % nbn;
  int tid = threadIdx.x;
  int w = tid >> 6, l = tid & 63;
  int lh = l & 15, lg = l >> 4;
  int wr = w >> 1, wc = w & 1;
  const size_t Kb = (size_t)K * 2;
  const char* Ab = (const char*)A + (size_t)(bm * 128) * Kb;
  const char* Bb = (const char*)Bt + (size_t)(bn * 128) * Kb;

  int c0 = w * 64 + l;
  int r0 = c0 >> 2, sw0 = ((c0 ^ (c0 >> 3)) & 3) << 4;
  int c1 = (4 + w) * 64 + l;
  int r1 = c1 >> 2, sw1 = ((c1 ^ (c1 >> 3)) & 3) << 4;

#define GSTAGE(sel, kt)                                                        \
  do {                                                                         \
    GLL16(Ab + (size_t)r0 * Kb + (size_t)(kt) * 64 + sw0,                      \
          (char*)lA[sel] + w * 1024);                                          \
    GLL16(Bb + (size_t)r0 * Kb + (size_t)(kt) * 64 + sw0,                      \
          (char*)lB[sel] + w * 1024);                                          \
    GLL16(Ab + (size_t)r1 * Kb + (size_t)(kt) * 64 + sw1,                      \
          (char*)lA[sel] + (4 + w) * 1024);                                    \
    GLL16(Bb + (size_t)r1 * Kb + (size_t)(kt) * 64 + sw1,                      \
          (char*)lB[sel] + (4 + w) * 1024);                                    \
  } while (0)

  const int swo = ((lg ^ (lh >> 1)) & 3) << 4;
  const int offA = (wr * 64 + lh) * 64 + swo;
  const int offB = (wc * 64 + lh) * 64 + swo;

  f32x4 acc[4][4] = {};
  const int nkt = K >> 5;
  GSTAGE(0, 0);
  __syncthreads();
  int cur = 0;
#pragma unroll 1
  for (int kt = 0; kt < nkt; ++kt) {
    if (kt + 1 < nkt) GSTAGE(cur ^ 1, kt + 1);
    const char* bufA = (const char*)lA[cur];
    const char* bufB = (const char*)lB[cur];
    bf16x8 af[4], bfr[4];
#pragma unroll
    for (int m = 0; m < 4; ++m)
      af[m] = *(const bf16x8*)(bufA + offA + m * 1024);
#pragma unroll
    for (int n = 0; n < 4; ++n)
      bfr[n] = *(const bf16x8*)(bufB + offB + n * 1024);
#pragma unroll
    for (int m = 0; m < 4; ++m)
#pragma unroll
      for (int n = 0; n < 4; ++n)
        acc[m][n] = MFMA16(af[m], bfr[n], acc[m][n]);
    __syncthreads();
    cur ^= 1;
  }
#undef GSTAGE

#pragma unroll
  for (int m = 0; m < 4; ++m) {
    int row0 = bm * 128 + wr * 64 + m * 16 + lg * 4;
#pragma unroll
    for (int n = 0; n < 4; ++n) {
      int col = bn * 128 + wc * 64 + n * 16 + lh;
      float bv = bias[col];
#pragma unroll
      for (int r = 0; r < 4; ++r) {
        int row = row0 + r;
        float v = acc[m][n][r] + bv;
        if (GELU) v = 0.5f * v * (1.0f + erff(v * 0.70710678118f));
        if (HAS_RES) v += res[(size_t)row * N + col];
        if (OUT_BF16) ((u16*)Cout)[(size_t)row * N + col] = f2bf(v);
        else ((float*)Cout)[(size_t)row * N + col] = v;
      }
    }
  }
  (void)M;
}

// --------------------------- causal flash attention -------------------------
__global__ __launch_bounds__(256, 4) void attn_kernel(
    const u16* __restrict__ qkv, const u16* __restrict__ vt,
    u16* __restrict__ out)
{
  __shared__ u16 Ks[2][4096];
  __shared__ u16 Vs[2][4096];
  __shared__ u16 Ps[4][1024];

  const float C = 0.18033688011f;  // 0.125 * log2(e)

  int bid = blockIdx.x;
  int pi = bid >> 6, bh = bid & 63;
  int b = bh >> 4, h = bh & 15;
  int tid = threadIdx.x;
  int w = tid >> 6, l = tid & 63;
  int lh = l & 15, lg = l >> 4;
  int lh7 = lh & 7;

  const char* kg = (const char*)qkv + (size_t)(b * 2048) * 6144 + 2048 + h * 128;
  const char* vg = (const char*)vt + (size_t)((b * 16 + h) * 64) * 4096;
  char* pbw = (char*)Ps[w] + lh * 128;

#pragma unroll 1
  for (int half = 0; half < 2; ++half) {
    int qb = half ? (31 - pi) : pi;
    int q0 = qb * 64 + w * 16;
    const u16* qbase = qkv + ((size_t)(b * 2048) + q0) * 3072 + h * 64;
    bf16x8 aq0 = *(const bf16x8*)(qbase + (size_t)lh * 3072 + lg * 8);
    bf16x8 aq1 = *(const bf16x8*)(qbase + (size_t)lh * 3072 + 32 + lg * 8);

    f32x4 o[4] = {};
    float m = -1e30f;
    float lsum = 0.f;
    int nt = qb + 1;

    __syncthreads();
#pragma unroll
    for (int i = 0; i < 2; ++i) {
      int u = tid + i * 256;
      int row = u >> 3, uc = u & 7, sw = uc ^ (row & 7);
      GLL16(kg + (size_t)row * 6144 + sw * 16,
            (char*)Ks[0] + (size_t)(i * 256 + w * 64) * 16);
      GLL16(vg + (size_t)row * 4096 + sw * 16,
            (char*)Vs[0] + (size_t)(i * 256 + w * 64) * 16);
    }

#pragma unroll 1
    for (int kt = 0; kt < nt; ++kt) {
      int cur = kt & 1;
      __syncthreads();
      if (kt + 1 < nt) {
        int nxt = cur ^ 1;
        size_t kofs = (size_t)(kt + 1) * 64;
#pragma unroll
        for (int i = 0; i < 2; ++i) {
          int u = tid + i * 256;
          int row = u >> 3, uc = u & 7, sw = uc ^ (row & 7);
          GLL16(kg + (kofs + row) * 6144 + sw * 16,
                (char*)Ks[nxt] + (size_t)(i * 256 + w * 64) * 16);
          GLL16(vg + (size_t)row * 4096 + kofs * 2 + sw * 16,
                (char*)Vs[nxt] + (size_t)(i * 256 + w * 64) * 16);
        }
      }
      const char* kbuf = (const char*)Ks[cur];
      f32x4 s[4];
#pragma unroll
      for (int kb = 0; kb < 4; ++kb) {
        int row = kb * 16 + lh;
        const char* rp = kbuf + row * 128;
        bf16x8 a0 = *(const bf16x8*)(rp + ((lg ^ lh7) << 4));
        bf16x8 a1 = *(const bf16x8*)(rp + (((4 + lg) ^ lh7) << 4));
        f32x4 z = {0.f, 0.f, 0.f, 0.f};
        z = MFMA16(a0, aq0, z);
        z = MFMA16(a1, aq1, z);
        s[kb] = z;
      }
      if (kt == qb) {
        int qin = w * 16 + lh;
#pragma unroll
        for (int kb = 0; kb < 4; ++kb)
#pragma unroll
          for (int r = 0; r < 4; ++r)
            if (kb * 16 + lg * 4 + r > qin) s[kb][r] = -1e30f;
      }
      float tm = fmaxf(fmaxf(s[0][0], s[0][1]), fmaxf(s[0][2], s[0][3]));
#pragma unroll
      for (int kb = 1; kb < 4; ++kb)
        tm = fmaxf(tm, fmaxf(fmaxf(s[kb][0], s[kb][1]), fmaxf(s[kb][2], s[kb][3])));
      tm = fmaxf(tm, __shfl_xor(tm, 16));
      tm = fmaxf(tm, __shfl_xor(tm, 32));
      if (__any(tm > m + 64.0f)) {
        float nm = fmaxf(m, tm);
        float f = __builtin_amdgcn_exp2f((m - nm) * C);
        m = nm; lsum *= f;
#pragma unroll
        for (int db = 0; db < 4; ++db)
#pragma unroll
          for (int r = 0; r < 4; ++r) o[db][r] *= f;
      }
      float mc = m * C;
      float ps = 0.f;
#pragma unroll
      for (int kb = 0; kb < 4; ++kb)
#pragma unroll
        for (int r = 0; r < 4; ++r) {
          float p = __builtin_amdgcn_exp2f(fmaf(s[kb][r], C, -mc));
          s[kb][r] = p;
          ps += p;
        }
      ps += __shfl_xor(ps, 16);
      ps += __shfl_xor(ps, 32);
      lsum += ps;
#pragma unroll
      for (int kb = 0; kb < 4; ++kb) {
        unsigned lo, hi;
        asm("v_cvt_pk_bf16_f32 %0, %1, %2" : "=v"(lo) : "v"(s[kb][0]), "v"(s[kb][1]));
        asm("v_cvt_pk_bf16_f32 %0, %1, %2" : "=v"(hi) : "v"(s[kb][2]), "v"(s[kb][3]));
        int unit = kb * 2 + (lg >> 1);
        uint2 val; val.x = lo; val.y = hi;
        *(uint2*)(pbw + ((unit ^ lh7) << 4) + ((lg & 1) << 3)) = val;
      }
      bf16x8 pa0 = *(const bf16x8*)(pbw + ((lg ^ lh7) << 4));
      bf16x8 pa1 = *(const bf16x8*)(pbw + (((4 + lg) ^ lh7) << 4));
      const char* vbuf = (const char*)Vs[cur];
#pragma unroll
      for (int db = 0; db < 4; ++db) {
        int row = db * 16 + lh;
        const char* rp = vbuf + row * 128;
        bf16x8 v0 = *(const bf16x8*)(rp + ((lg ^ lh7) << 4));
        bf16x8 v1 = *(const bf16x8*)(rp + (((4 + lg) ^ lh7) << 4));
        o[db] = MFMA16(v0, pa0, o[db]);
        o[db] = MFMA16(v1, pa1, o[db]);
      }
    }
    float rinv = 1.0f / lsum;
    u16* ob = out + ((size_t)(b * 2048) + q0 + lh) * 1024 + h * 64;
#pragma unroll
    for (int db = 0; db < 4; ++db) {
      ushort4 pk;
      pk.x = f2bf(o[db][0] * rinv);
      pk.y = f2bf(o[db][1] * rinv);
      pk.z = f2bf(o[db][2] * rinv);
      pk.w = f2bf(o[db][3] * rinv);
      *(ushort4*)(ob + db * 16 + lg * 4) = pk;
    }
  }
}

// ---------------------------------------------------------------------------
extern "C" void kernel_launch(void* const* d_in, const int* in_sizes, int n_in,
                              void* d_out, int out_size, void* d_ws, size_t ws_size,
                              hipStream_t stream) {
  const float* x     = (const float*)d_in[0];
  const float* ln1_g = (const float*)d_in[1];
  const float* ln1_b = (const float*)d_in[2];
  const float* w_qkv = (const float*)d_in[3];
  const float* b_qkv = (const float*)d_in[4];
  const float* w_out = (const float*)d_in[5];
  const float* b_out = (const float*)d_in[6];
  const float* ln2_g = (const float*)d_in[7];
  const float* ln2_b = (const float*)d_in[8];
  const float* w1    = (const float*)d_in[9];
  const float* b1    = (const float*)d_in[10];
  const float* w2    = (const float*)d_in[11];
  const float* b2    = (const float*)d_in[12];

  char* ws = (char*)d_ws;
  // liveness-aliased layout, 142.6 MB total
  u16* wqkvT = (u16*)(ws + 0);          // 6.29 MB
  u16* woutT = (u16*)(ws + 6291456);    // 2.10 MB
  u16* w1T   = (u16*)(ws + 8388608);    // 8.39 MB
  u16* w2T   = (u16*)(ws + 16777216);   // 8.39 MB
  u16* qkv   = (u16*)(ws + 25165824);   // 50.3 MB  [b,l,3,h,d]
  u16* ffn1  = (u16*)(ws + 25165824);   // 67.1 MB  (aliases qkv+vt, both dead)
  u16* vtb   = (u16*)(ws + 75497472);   // 16.8 MB  [b,h,d,l]
  u16* lnb   = (u16*)(ws + 92274688);   // 16.8 MB  (ln1 out / attn out / ln2 out)
  u16* attn  = lnb;
  float* h   = (float*)(ws + 125829120);// 33.6 MB

  wt_kernel<<<dim3(96, 32), 256, 0, stream>>>(w_qkv, wqkvT, 1024, 3072);
  wt_kernel<<<dim3(32, 32), 256, 0, stream>>>(w_out, woutT, 1024, 1024);
  wt_kernel<<<dim3(128, 32), 256, 0, stream>>>(w1, w1T, 1024, 4096);
  wt_kernel<<<dim3(32, 128), 256, 0, stream>>>(w2, w2T, 4096, 1024);

  ln_kernel<<<8192, 256, 0, stream>>>(x, ln1_g, ln1_b, lnb);
  // QKV: M=8192 N=3072 K=1024, 256x256 BK=64 -> 384 wg
  gemm256_kernel<0, 1><<<384, 512, 0, stream>>>(lnb, wqkvT, b_qkv, qkv, 8192, 3072, 1024);
  vt_kernel<<<2048, 256, 0, stream>>>(qkv, vtb);
  attn_kernel<<<1024, 256, 0, stream>>>(qkv, vtb, attn);
  // out-proj: M=8192 N=1024 K=1024, 128x128 (R7) -> 512 wg
  gemm_kernel<0, 1, 0><<<512, 256, 0, stream>>>(attn, woutT, b_out, x, h, 8192, 1024, 1024);
  ln_kernel<<<8192, 256, 0, stream>>>(h, ln2_g, ln2_b, lnb);
  // FFN1: M=8192 N=4096 K=1024, 256x256 BK=64 -> 512 wg
  gemm256_kernel<1, 1><<<512, 512, 0, stream>>>(lnb, w1T, b1, ffn1, 8192, 4096, 1024);
  // FFN2: M=8192 N=1024 K=4096, 128x128 (R7) -> 512 wg
  gemm_kernel<0, 1, 0><<<512, 256, 0, stream>>>(ffn1, w2T, b2, h, (float*)d_out, 8192, 1024, 4096);
}

// Round 8
// 388.513 us; speedup vs baseline: 1.2161x; 1.0534x over previous
//
#include <hip/hip_runtime.h>
#include <hip/hip_bf16.h>

// ---------------------------------------------------------------------------
// TransformerBlock: LN1 -> QKV GEMM -> causal flash attn -> out-proj(+x) -> h
//                   LN2 -> FFN1(+gelu) -> FFN2(+h) -> out
// GEMMs (R11): hybrid routing of the two session-verified kernels:
//  * K=1024 GEMMs (QKV, out-proj, FFN1): R7 2-buf 128x128 syncthreads-drain
//    (best measured for short K: FFN1 134.5us).
//  * K=4096 GEMM (FFN2): R5 ring-of-3 counted-vmcnt 128x128 (long K-loop
//    amortizes the counted pipeline; R5's all-ring3 build was best total
//    390.8us despite worse FFN1 => ~24us gain lived in the long-K/other
//    GEMMs).
//  Both use the verified zero-conflict XOR unit swizzle + XCD swizzle.
//  512-thr/128KB 256^2 quadrant closed: R4/R6/R8/R10 all ~168-178us.
// Attn (R2): swapped QK^T, LDS-staged K/V, defer-max, cvt_pk P packing.
// ---------------------------------------------------------------------------

typedef float f32x4 __attribute__((ext_vector_type(4)));
typedef __bf16 bf16x8 __attribute__((ext_vector_type(8)));
typedef unsigned short u16;

#define MFMA16(a, b, c) __builtin_amdgcn_mfma_f32_16x16x32_bf16((a), (b), (c), 0, 0, 0)

#define GLL16(g, l)                                                            \
  __builtin_amdgcn_global_load_lds(                                            \
      (__attribute__((address_space(1))) void*)(g),                            \
      (__attribute__((address_space(3))) void*)(l), 16, 0, 0)

__device__ __forceinline__ u16 f2bf(float f) {
  union { float f; unsigned int u; } x; x.f = f;
  unsigned int r = x.u + 0x7fffu + ((x.u >> 16) & 1u);
  return (u16)(r >> 16);
}

// ---------------- LayerNorm: fp32 in -> bf16 out, one row per block ---------
__global__ __launch_bounds__(256) void ln_kernel(
    const float* __restrict__ x, const float* __restrict__ g,
    const float* __restrict__ b, u16* __restrict__ y)
{
  int row = blockIdx.x;
  int t = threadIdx.x;
  const float4* xr = (const float4*)(x + (size_t)row * 1024);
  float4 v = xr[t];
  float s  = v.x + v.y + v.z + v.w;
  float ss = v.x*v.x + v.y*v.y + v.z*v.z + v.w*v.w;
#pragma unroll
  for (int off = 1; off < 64; off <<= 1) {
    s  += __shfl_xor(s, off);
    ss += __shfl_xor(ss, off);
  }
  __shared__ float red[8];
  int w = t >> 6;
  if ((t & 63) == 0) { red[w*2] = s; red[w*2+1] = ss; }
  __syncthreads();
  s  = red[0] + red[2] + red[4] + red[6];
  ss = red[1] + red[3] + red[5] + red[7];
  float mu  = s * (1.0f / 1024.0f);
  float var = ss * (1.0f / 1024.0f) - mu * mu;
  float rs  = rsqrtf(var + 1e-5f);
  float4 gg = ((const float4*)g)[t];
  float4 bb = ((const float4*)b)[t];
  ushort4 o;
  o.x = f2bf((v.x - mu) * rs * gg.x + bb.x);
  o.y = f2bf((v.y - mu) * rs * gg.y + bb.y);
  o.z = f2bf((v.z - mu) * rs * gg.z + bb.z);
  o.w = f2bf((v.w - mu) * rs * gg.w + bb.w);
  ((ushort4*)y)[(size_t)row * 256 + t] = o;
}

// ------------- weight convert+transpose: W[K][N] fp32 -> Wt[N][K] bf16 ------
__global__ __launch_bounds__(256) void wt_kernel(
    const float* __restrict__ W, u16* __restrict__ Wt, int K, int N)
{
  __shared__ u16 tile[32][33];
  int n0 = blockIdx.x * 32, k0 = blockIdx.y * 32;
  int t = threadIdx.x, tr = t >> 5, tc = t & 31;
#pragma unroll
  for (int i = 0; i < 4; ++i) {
    int k = k0 + tr + i * 8;
    tile[tc][tr + i * 8] = f2bf(W[(size_t)k * N + n0 + tc]);
  }
  __syncthreads();
#pragma unroll
  for (int i = 0; i < 4; ++i) {
    int n = n0 + tr + i * 8;
    Wt[(size_t)n * K + k0 + tc] = tile[tr + i * 8][tc];
  }
}

// ------------- V transpose: qkv[b,l,2,h,d] bf16 -> Vt[b,h,d,l] bf16 ---------
__global__ __launch_bounds__(256) void vt_kernel(
    const u16* __restrict__ qkv, u16* __restrict__ vt)
{
  __shared__ u16 tile[64][65];
  int bid = blockIdx.x;
  int lt = bid & 31, h = (bid >> 5) & 15, b = bid >> 9;
  int t = threadIdx.x;
  int tr = t >> 4, tc4 = (t & 15) * 4;
  const u16* src = qkv + ((size_t)(b * 2048 + lt * 64)) * 3072 + 2048 + h * 64;
#pragma unroll
  for (int i = 0; i < 4; ++i) {
    int ll = tr + i * 16;
    ushort4 v = *(const ushort4*)(src + (size_t)ll * 3072 + tc4);
    tile[ll][tc4] = v.x; tile[ll][tc4+1] = v.y; tile[ll][tc4+2] = v.z; tile[ll][tc4+3] = v.w;
  }
  __syncthreads();
  u16* dst = vt + ((size_t)(b * 16 + h) * 64) * 2048 + lt * 64;
#pragma unroll
  for (int i = 0; i < 4; ++i) {
    int d = tr + i * 16;
    ushort4 o;
    o.x = tile[tc4][d]; o.y = tile[tc4+1][d]; o.z = tile[tc4+2][d]; o.w = tile[tc4+3][d];
    *(ushort4*)(dst + (size_t)d * 2048 + tc4) = o;
  }
}

// ------------------------- GEMM 128x128 2-buf (R7, verified) ----------------
// Best measured for K=1024 shapes. syncthreads-drained m97 structure +
// zero-conflict swizzle.
template<int GELU, int HAS_RES, int OUT_BF16>
__global__ __launch_bounds__(256, 2) void gemm_kernel(
    const u16* __restrict__ A, const u16* __restrict__ Bt,
    const float* __restrict__ bias, const float* __restrict__ res,
    void* __restrict__ Cout, int M, int N, int K)
{
  __shared__ u16 lA[2][128 * 32];
  __shared__ u16 lB[2][128 * 32];
  const int nbn = N >> 7;
  int nwg = gridDim.x;
  int wg = blockIdx.x;
  if ((nwg & 7) == 0) wg = (wg & 7) * (nwg >> 3) + (wg >> 3);
  int bm = wg / nbn, bn = wg % nbn;
  int tid = threadIdx.x;
  int w = tid >> 6, l = tid & 63;
  int lh = l & 15, lg = l >> 4;
  int wr = w >> 1, wc = w & 1;
  const size_t Kb = (size_t)K * 2;
  const char* Ab = (const char*)A + (size_t)(bm * 128) * Kb;
  const char* Bb = (const char*)Bt + (size_t)(bn * 128) * Kb;

  int c0 = w * 64 + l;
  int r0 = c0 >> 2, sw0 = ((c0 ^ (c0 >> 3)) & 3) << 4;
  int c1 = (4 + w) * 64 + l;
  int r1 = c1 >> 2, sw1 = ((c1 ^ (c1 >> 3)) & 3) << 4;

#define GSTAGE(sel, kt)                                                        \
  do {                                                                         \
    GLL16(Ab + (size_t)r0 * Kb + (size_t)(kt) * 64 + sw0,                      \
          (char*)lA[sel] + w * 1024);                                          \
    GLL16(Bb + (size_t)r0 * Kb + (size_t)(kt) * 64 + sw0,                      \
          (char*)lB[sel] + w * 1024);                                          \
    GLL16(Ab + (size_t)r1 * Kb + (size_t)(kt) * 64 + sw1,                      \
          (char*)lA[sel] + (4 + w) * 1024);                                    \
    GLL16(Bb + (size_t)r1 * Kb + (size_t)(kt) * 64 + sw1,                      \
          (char*)lB[sel] + (4 + w) * 1024);                                    \
  } while (0)

  const int swo = ((lg ^ (lh >> 1)) & 3) << 4;
  const int offA = (wr * 64 + lh) * 64 + swo;
  const int offB = (wc * 64 + lh) * 64 + swo;

  f32x4 acc[4][4] = {};
  const int nkt = K >> 5;
  GSTAGE(0, 0);
  __syncthreads();
  int cur = 0;
#pragma unroll 1
  for (int kt = 0; kt < nkt; ++kt) {
    if (kt + 1 < nkt) GSTAGE(cur ^ 1, kt + 1);
    const char* bufA = (const char*)lA[cur];
    const char* bufB = (const char*)lB[cur];
    bf16x8 af[4], bfr[4];
#pragma unroll
    for (int m = 0; m < 4; ++m)
      af[m] = *(const bf16x8*)(bufA + offA + m * 1024);
#pragma unroll
    for (int n = 0; n < 4; ++n)
      bfr[n] = *(const bf16x8*)(bufB + offB + n * 1024);
#pragma unroll
    for (int m = 0; m < 4; ++m)
#pragma unroll
      for (int n = 0; n < 4; ++n)
        acc[m][n] = MFMA16(af[m], bfr[n], acc[m][n]);
    __syncthreads();
    cur ^= 1;
  }
#undef GSTAGE

#pragma unroll
  for (int m = 0; m < 4; ++m) {
    int row0 = bm * 128 + wr * 64 + m * 16 + lg * 4;
#pragma unroll
    for (int n = 0; n < 4; ++n) {
      int col = bn * 128 + wc * 64 + n * 16 + lh;
      float bv = bias[col];
#pragma unroll
      for (int r = 0; r < 4; ++r) {
        int row = row0 + r;
        float v = acc[m][n][r] + bv;
        if (GELU) v = 0.5f * v * (1.0f + erff(v * 0.70710678118f));
        if (HAS_RES) v += res[(size_t)row * N + col];
        if (OUT_BF16) ((u16*)Cout)[(size_t)row * N + col] = f2bf(v);
        else ((float*)Cout)[(size_t)row * N + col] = v;
      }
    }
  }
  (void)M;
}

// --------------------- GEMM 128x128 ring-3 (R5, verified) -------------------
// For long-K GEMMs (FFN2, K=4096): ring-of-3 buffers, distance-2 prefetch,
// counted s_waitcnt vmcnt(4) + single s_barrier per K-step (no full drain
// until tail) — amortizes over 128 K-steps.
template<int GELU, int HAS_RES, int OUT_BF16>
__global__ __launch_bounds__(256, 2) void gemm_ring3(
    const u16* __restrict__ A, const u16* __restrict__ Bt,
    const float* __restrict__ bias, const float* __restrict__ res,
    void* __restrict__ Cout, int M, int N, int K)
{
  __shared__ u16 lA[3][128 * 32];
  __shared__ u16 lB[3][128 * 32];
  const int nbn = N >> 7;
  int nwg = gridDim.x;
  int wg = blockIdx.x;
  if ((nwg & 7) == 0) wg = (wg & 7) * (nwg >> 3) + (wg >> 3);
  int bm = wg / nbn, bn = wg % nbn;
  int tid = threadIdx.x;
  int w = tid >> 6, l = tid & 63;
  int lh = l & 15, lg = l >> 4;
  int wr = w >> 1, wc = w & 1;
  const size_t Kb = (size_t)K * 2;
  const char* Ab = (const char*)A + (size_t)(bm * 128) * Kb;
  const char* Bb = (const char*)Bt + (size_t)(bn * 128) * Kb;

  int c0 = w * 64 + l;
  int r0 = c0 >> 2, sw0 = ((c0 ^ (c0 >> 3)) & 3) << 4;
  int c1 = (4 + w) * 64 + l;
  int r1 = c1 >> 2, sw1 = ((c1 ^ (c1 >> 3)) & 3) << 4;

#define GSTAGE(sel, kt)                                                        \
  do {                                                                         \
    GLL16(Ab + (size_t)r0 * Kb + (size_t)(kt) * 64 + sw0,                      \
          (char*)lA[sel] + w * 1024);                                          \
    GLL16(Bb + (size_t)r0 * Kb + (size_t)(kt) * 64 + sw0,                      \
          (char*)lB[sel] + w * 1024);                                          \
    GLL16(Ab + (size_t)r1 * Kb + (size_t)(kt) * 64 + sw1,                      \
          (char*)lA[sel] + (4 + w) * 1024);                                    \
    GLL16(Bb + (size_t)r1 * Kb + (size_t)(kt) * 64 + sw1,                      \
          (char*)lB[sel] + (4 + w) * 1024);                                    \
  } while (0)

  const int swo = ((lg ^ (lh >> 1)) & 3) << 4;
  const int offA = (wr * 64 + lh) * 64 + swo;
  const int offB = (wc * 64 + lh) * 64 + swo;

  f32x4 acc[4][4] = {};
  const int nkt = K >> 5;
  GSTAGE(0, 0);
  GSTAGE(1, 1);
  asm volatile("s_waitcnt vmcnt(4)" ::: "memory");   // tile 0 resident
  __builtin_amdgcn_s_barrier();
  __builtin_amdgcn_sched_barrier(0);

  int cur = 0, s2 = 2;
#pragma unroll 1
  for (int t = 0; t < nkt; ++t) {
    const char* bufA = (const char*)lA[cur];
    const char* bufB = (const char*)lB[cur];
    bf16x8 af[4], bfr[4];
#pragma unroll
    for (int m = 0; m < 4; ++m)
      af[m] = *(const bf16x8*)(bufA + offA + m * 1024);
#pragma unroll
    for (int n = 0; n < 4; ++n)
      bfr[n] = *(const bf16x8*)(bufB + offB + n * 1024);
    if (t + 2 < nkt) GSTAGE(s2, t + 2);   // async, lands 2 steps ahead
    __builtin_amdgcn_s_setprio(1);
#pragma unroll
    for (int m = 0; m < 4; ++m)
#pragma unroll
      for (int n = 0; n < 4; ++n)
        acc[m][n] = MFMA16(af[m], bfr[n], acc[m][n]);
    __builtin_amdgcn_s_setprio(0);
    if (t < nkt - 1) {
      __builtin_amdgcn_sched_barrier(0);
      if (t < nkt - 2) asm volatile("s_waitcnt vmcnt(4)" ::: "memory");
      else             asm volatile("s_waitcnt vmcnt(0)" ::: "memory");
      __builtin_amdgcn_s_barrier();      // tile t+1 resident for all waves
      __builtin_amdgcn_sched_barrier(0);
    }
    cur = (cur == 2) ? 0 : cur + 1;
    s2  = (s2 == 2) ? 0 : s2 + 1;
  }
#undef GSTAGE

#pragma unroll
  for (int m = 0; m < 4; ++m) {
    int row0 = bm * 128 + wr * 64 + m * 16 + lg * 4;
#pragma unroll
    for (int n = 0; n < 4; ++n) {
      int col = bn * 128 + wc * 64 + n * 16 + lh;
      float bv = bias[col];
#pragma unroll
      for (int r = 0; r < 4; ++r) {
        int row = row0 + r;
        float v = acc[m][n][r] + bv;
        if (GELU) v = 0.5f * v * (1.0f + erff(v * 0.70710678118f));
        if (HAS_RES) v += res[(size_t)row * N + col];
        if (OUT_BF16) ((u16*)Cout)[(size_t)row * N + col] = f2bf(v);
        else ((float*)Cout)[(size_t)row * N + col] = v;
      }
    }
  }
  (void)M;
}

// --------------------------- causal flash attention -------------------------
__global__ __launch_bounds__(256, 4) void attn_kernel(
    const u16* __restrict__ qkv, const u16* __restrict__ vt,
    u16* __restrict__ out)
{
  __shared__ u16 Ks[2][4096];
  __shared__ u16 Vs[2][4096];
  __shared__ u16 Ps[4][1024];

  const float C = 0.18033688011f;  // 0.125 * log2(e)

  int bid = blockIdx.x;
  int pi = bid >> 6, bh = bid & 63;
  int b = bh >> 4, h = bh & 15;
  int tid = threadIdx.x;
  int w = tid >> 6, l = tid & 63;
  int lh = l & 15, lg = l >> 4;
  int lh7 = lh & 7;

  const char* kg = (const char*)qkv + (size_t)(b * 2048) * 6144 + 2048 + h * 128;
  const char* vg = (const char*)vt + (size_t)((b * 16 + h) * 64) * 4096;
  char* pbw = (char*)Ps[w] + lh * 128;

#pragma unroll 1
  for (int half = 0; half < 2; ++half) {
    int qb = half ? (31 - pi) : pi;
    int q0 = qb * 64 + w * 16;
    const u16* qbase = qkv + ((size_t)(b * 2048) + q0) * 3072 + h * 64;
    bf16x8 aq0 = *(const bf16x8*)(qbase + (size_t)lh * 3072 + lg * 8);
    bf16x8 aq1 = *(const bf16x8*)(qbase + (size_t)lh * 3072 + 32 + lg * 8);

    f32x4 o[4] = {};
    float m = -1e30f;
    float lsum = 0.f;
    int nt = qb + 1;

    __syncthreads();
#pragma unroll
    for (int i = 0; i < 2; ++i) {
      int u = tid + i * 256;
      int row = u >> 3, uc = u & 7, sw = uc ^ (row & 7);
      GLL16(kg + (size_t)row * 6144 + sw * 16,
            (char*)Ks[0] + (size_t)(i * 256 + w * 64) * 16);
      GLL16(vg + (size_t)row * 4096 + sw * 16,
            (char*)Vs[0] + (size_t)(i * 256 + w * 64) * 16);
    }

#pragma unroll 1
    for (int kt = 0; kt < nt; ++kt) {
      int cur = kt & 1;
      __syncthreads();
      if (kt + 1 < nt) {
        int nxt = cur ^ 1;
        size_t kofs = (size_t)(kt + 1) * 64;
#pragma unroll
        for (int i = 0; i < 2; ++i) {
          int u = tid + i * 256;
          int row = u >> 3, uc = u & 7, sw = uc ^ (row & 7);
          GLL16(kg + (kofs + row) * 6144 + sw * 16,
                (char*)Ks[nxt] + (size_t)(i * 256 + w * 64) * 16);
          GLL16(vg + (size_t)row * 4096 + kofs * 2 + sw * 16,
                (char*)Vs[nxt] + (size_t)(i * 256 + w * 64) * 16);
        }
      }
      const char* kbuf = (const char*)Ks[cur];
      f32x4 s[4];
#pragma unroll
      for (int kb = 0; kb < 4; ++kb) {
        int row = kb * 16 + lh;
        const char* rp = kbuf + row * 128;
        bf16x8 a0 = *(const bf16x8*)(rp + ((lg ^ lh7) << 4));
        bf16x8 a1 = *(const bf16x8*)(rp + (((4 + lg) ^ lh7) << 4));
        f32x4 z = {0.f, 0.f, 0.f, 0.f};
        z = MFMA16(a0, aq0, z);
        z = MFMA16(a1, aq1, z);
        s[kb] = z;
      }
      if (kt == qb) {
        int qin = w * 16 + lh;
#pragma unroll
        for (int kb = 0; kb < 4; ++kb)
#pragma unroll
          for (int r = 0; r < 4; ++r)
            if (kb * 16 + lg * 4 + r > qin) s[kb][r] = -1e30f;
      }
      float tm = fmaxf(fmaxf(s[0][0], s[0][1]), fmaxf(s[0][2], s[0][3]));
#pragma unroll
      for (int kb = 1; kb < 4; ++kb)
        tm = fmaxf(tm, fmaxf(fmaxf(s[kb][0], s[kb][1]), fmaxf(s[kb][2], s[kb][3])));
      tm = fmaxf(tm, __shfl_xor(tm, 16));
      tm = fmaxf(tm, __shfl_xor(tm, 32));
      if (__any(tm > m + 64.0f)) {
        float nm = fmaxf(m, tm);
        float f = __builtin_amdgcn_exp2f((m - nm) * C);
        m = nm; lsum *= f;
#pragma unroll
        for (int db = 0; db < 4; ++db)
#pragma unroll
          for (int r = 0; r < 4; ++r) o[db][r] *= f;
      }
      float mc = m * C;
      float ps = 0.f;
#pragma unroll
      for (int kb = 0; kb < 4; ++kb)
#pragma unroll
        for (int r = 0; r < 4; ++r) {
          float p = __builtin_amdgcn_exp2f(fmaf(s[kb][r], C, -mc));
          s[kb][r] = p;
          ps += p;
        }
      ps += __shfl_xor(ps, 16);
      ps += __shfl_xor(ps, 32);
      lsum += ps;
#pragma unroll
      for (int kb = 0; kb < 4; ++kb) {
        unsigned lo, hi;
        asm("v_cvt_pk_bf16_f32 %0, %1, %2" : "=v"(lo) : "v"(s[kb][0]), "v"(s[kb][1]));
        asm("v_cvt_pk_bf16_f32 %0, %1, %2" : "=v"(hi) : "v"(s[kb][2]), "v"(s[kb][3]));
        int unit = kb * 2 + (lg >> 1);
        uint2 val; val.x = lo; val.y = hi;
        *(uint2*)(pbw + ((unit ^ lh7) << 4) + ((lg & 1) << 3)) = val;
      }
      bf16x8 pa0 = *(const bf16x8*)(pbw + ((lg ^ lh7) << 4));
      bf16x8 pa1 = *(const bf16x8*)(pbw + (((4 + lg) ^ lh7) << 4));
      const char* vbuf = (const char*)Vs[cur];
#pragma unroll
      for (int db = 0; db < 4; ++db) {
        int row = db * 16 + lh;
        const char* rp = vbuf + row * 128;
        bf16x8 v0 = *(const bf16x8*)(rp + ((lg ^ lh7) << 4));
        bf16x8 v1 = *(const bf16x8*)(rp + (((4 + lg) ^ lh7) << 4));
        o[db] = MFMA16(v0, pa0, o[db]);
        o[db] = MFMA16(v1, pa1, o[db]);
      }
    }
    float rinv = 1.0f / lsum;
    u16* ob = out + ((size_t)(b * 2048) + q0 + lh) * 1024 + h * 64;
#pragma unroll
    for (int db = 0; db < 4; ++db) {
      ushort4 pk;
      pk.x = f2bf(o[db][0] * rinv);
      pk.y = f2bf(o[db][1] * rinv);
      pk.z = f2bf(o[db][2] * rinv);
      pk.w = f2bf(o[db][3] * rinv);
      *(ushort4*)(ob + db * 16 + lg * 4) = pk;
    }
  }
}

// ---------------------------------------------------------------------------
extern "C" void kernel_launch(void* const* d_in, const int* in_sizes, int n_in,
                              void* d_out, int out_size, void* d_ws, size_t ws_size,
                              hipStream_t stream) {
  const float* x     = (const float*)d_in[0];
  const float* ln1_g = (const float*)d_in[1];
  const float* ln1_b = (const float*)d_in[2];
  const float* w_qkv = (const float*)d_in[3];
  const float* b_qkv = (const float*)d_in[4];
  const float* w_out = (const float*)d_in[5];
  const float* b_out = (const float*)d_in[6];
  const float* ln2_g = (const float*)d_in[7];
  const float* ln2_b = (const float*)d_in[8];
  const float* w1    = (const float*)d_in[9];
  const float* b1    = (const float*)d_in[10];
  const float* w2    = (const float*)d_in[11];
  const float* b2    = (const float*)d_in[12];

  char* ws = (char*)d_ws;
  // liveness-aliased layout, 142.6 MB total
  u16* wqkvT = (u16*)(ws + 0);          // 6.29 MB
  u16* woutT = (u16*)(ws + 6291456);    // 2.10 MB
  u16* w1T   = (u16*)(ws + 8388608);    // 8.39 MB
  u16* w2T   = (u16*)(ws + 16777216);   // 8.39 MB
  u16* qkv   = (u16*)(ws + 25165824);   // 50.3 MB  [b,l,3,h,d]
  u16* ffn1  = (u16*)(ws + 25165824);   // 67.1 MB  (aliases qkv+vt, both dead)
  u16* vtb   = (u16*)(ws + 75497472);   // 16.8 MB  [b,h,d,l]
  u16* lnb   = (u16*)(ws + 92274688);   // 16.8 MB  (ln1 out / attn out / ln2 out)
  u16* attn  = lnb;
  float* h   = (float*)(ws + 125829120);// 33.6 MB

  wt_kernel<<<dim3(96, 32), 256, 0, stream>>>(w_qkv, wqkvT, 1024, 3072);
  wt_kernel<<<dim3(32, 32), 256, 0, stream>>>(w_out, woutT, 1024, 1024);
  wt_kernel<<<dim3(128, 32), 256, 0, stream>>>(w1, w1T, 1024, 4096);
  wt_kernel<<<dim3(32, 128), 256, 0, stream>>>(w2, w2T, 4096, 1024);

  ln_kernel<<<8192, 256, 0, stream>>>(x, ln1_g, ln1_b, lnb);
  // QKV: K=1024 -> 2-buf
  gemm_kernel<0, 0, 1><<<1536, 256, 0, stream>>>(lnb, wqkvT, b_qkv, nullptr, qkv, 8192, 3072, 1024);
  vt_kernel<<<2048, 256, 0, stream>>>(qkv, vtb);
  attn_kernel<<<1024, 256, 0, stream>>>(qkv, vtb, attn);
  // out-proj: K=1024 -> 2-buf
  gemm_kernel<0, 1, 0><<<512, 256, 0, stream>>>(attn, woutT, b_out, x, h, 8192, 1024, 1024);
  ln_kernel<<<8192, 256, 0, stream>>>(h, ln2_g, ln2_b, lnb);
  // FFN1: K=1024 -> 2-buf
  gemm_kernel<1, 0, 1><<<2048, 256, 0, stream>>>(lnb, w1T, b1, nullptr, ffn1, 8192, 4096, 1024);
  // FFN2: K=4096 -> ring-3 counted vmcnt (long K-loop amortizes pipeline)
  gemm_ring3<0, 1, 0><<<512, 256, 0, stream>>>(ffn1, w2T, b2, h, (float*)d_out, 8192, 1024, 4096);
}

// Round 9
// 384.778 us; speedup vs baseline: 1.2279x; 1.0097x over previous
//
#include <hip/hip_runtime.h>
#include <hip/hip_bf16.h>

// ---------------------------------------------------------------------------
// TransformerBlock: LN1 -> QKV GEMM -> causal flash attn -> out-proj(+x) -> h
//                   LN2 -> FFN1(+gelu) -> FFN2(+h) -> out
// GEMMs (R12): per-GEMM routing of the two session-verified kernels, from
//  the R5/R7/R11 ledger decomposition:
//   * ring-3 counted-vmcnt 128x128: QKV, out-proj, FFN2  (each measured
//     faster under ring-3; combined ~ -24us vs 2-buf)
//   * 2-buf syncthreads-drain 128x128: FFN1 only (ring-3 penalty +12.3us
//     there — gelu epilogue + largest grid)
//  Both kernels share the verified zero-conflict XOR unit swizzle and
//  XCD-chunked block swizzle. 512-thr/128KB 256^2 quadrant closed
//  (R4/R6/R8/R10 all ~168-178us).
// Attn (R2): swapped QK^T, LDS-staged K/V, defer-max, cvt_pk P packing.
// ---------------------------------------------------------------------------

typedef float f32x4 __attribute__((ext_vector_type(4)));
typedef __bf16 bf16x8 __attribute__((ext_vector_type(8)));
typedef unsigned short u16;

#define MFMA16(a, b, c) __builtin_amdgcn_mfma_f32_16x16x32_bf16((a), (b), (c), 0, 0, 0)

#define GLL16(g, l)                                                            \
  __builtin_amdgcn_global_load_lds(                                            \
      (__attribute__((address_space(1))) void*)(g),                            \
      (__attribute__((address_space(3))) void*)(l), 16, 0, 0)

__device__ __forceinline__ u16 f2bf(float f) {
  union { float f; unsigned int u; } x; x.f = f;
  unsigned int r = x.u + 0x7fffu + ((x.u >> 16) & 1u);
  return (u16)(r >> 16);
}

// ---------------- LayerNorm: fp32 in -> bf16 out, one row per block ---------
__global__ __launch_bounds__(256) void ln_kernel(
    const float* __restrict__ x, const float* __restrict__ g,
    const float* __restrict__ b, u16* __restrict__ y)
{
  int row = blockIdx.x;
  int t = threadIdx.x;
  const float4* xr = (const float4*)(x + (size_t)row * 1024);
  float4 v = xr[t];
  float s  = v.x + v.y + v.z + v.w;
  float ss = v.x*v.x + v.y*v.y + v.z*v.z + v.w*v.w;
#pragma unroll
  for (int off = 1; off < 64; off <<= 1) {
    s  += __shfl_xor(s, off);
    ss += __shfl_xor(ss, off);
  }
  __shared__ float red[8];
  int w = t >> 6;
  if ((t & 63) == 0) { red[w*2] = s; red[w*2+1] = ss; }
  __syncthreads();
  s  = red[0] + red[2] + red[4] + red[6];
  ss = red[1] + red[3] + red[5] + red[7];
  float mu  = s * (1.0f / 1024.0f);
  float var = ss * (1.0f / 1024.0f) - mu * mu;
  float rs  = rsqrtf(var + 1e-5f);
  float4 gg = ((const float4*)g)[t];
  float4 bb = ((const float4*)b)[t];
  ushort4 o;
  o.x = f2bf((v.x - mu) * rs * gg.x + bb.x);
  o.y = f2bf((v.y - mu) * rs * gg.y + bb.y);
  o.z = f2bf((v.z - mu) * rs * gg.z + bb.z);
  o.w = f2bf((v.w - mu) * rs * gg.w + bb.w);
  ((ushort4*)y)[(size_t)row * 256 + t] = o;
}

// ------------- weight convert+transpose: W[K][N] fp32 -> Wt[N][K] bf16 ------
__global__ __launch_bounds__(256) void wt_kernel(
    const float* __restrict__ W, u16* __restrict__ Wt, int K, int N)
{
  __shared__ u16 tile[32][33];
  int n0 = blockIdx.x * 32, k0 = blockIdx.y * 32;
  int t = threadIdx.x, tr = t >> 5, tc = t & 31;
#pragma unroll
  for (int i = 0; i < 4; ++i) {
    int k = k0 + tr + i * 8;
    tile[tc][tr + i * 8] = f2bf(W[(size_t)k * N + n0 + tc]);
  }
  __syncthreads();
#pragma unroll
  for (int i = 0; i < 4; ++i) {
    int n = n0 + tr + i * 8;
    Wt[(size_t)n * K + k0 + tc] = tile[tr + i * 8][tc];
  }
}

// ------------- V transpose: qkv[b,l,2,h,d] bf16 -> Vt[b,h,d,l] bf16 ---------
__global__ __launch_bounds__(256) void vt_kernel(
    const u16* __restrict__ qkv, u16* __restrict__ vt)
{
  __shared__ u16 tile[64][65];
  int bid = blockIdx.x;
  int lt = bid & 31, h = (bid >> 5) & 15, b = bid >> 9;
  int t = threadIdx.x;
  int tr = t >> 4, tc4 = (t & 15) * 4;
  const u16* src = qkv + ((size_t)(b * 2048 + lt * 64)) * 3072 + 2048 + h * 64;
#pragma unroll
  for (int i = 0; i < 4; ++i) {
    int ll = tr + i * 16;
    ushort4 v = *(const ushort4*)(src + (size_t)ll * 3072 + tc4);
    tile[ll][tc4] = v.x; tile[ll][tc4+1] = v.y; tile[ll][tc4+2] = v.z; tile[ll][tc4+3] = v.w;
  }
  __syncthreads();
  u16* dst = vt + ((size_t)(b * 16 + h) * 64) * 2048 + lt * 64;
#pragma unroll
  for (int i = 0; i < 4; ++i) {
    int d = tr + i * 16;
    ushort4 o;
    o.x = tile[tc4][d]; o.y = tile[tc4+1][d]; o.z = tile[tc4+2][d]; o.w = tile[tc4+3][d];
    *(ushort4*)(dst + (size_t)d * 2048 + tc4) = o;
  }
}

// ------------------------- GEMM 128x128 2-buf (R7, verified) ----------------
// For FFN1 only (K=1024, gelu epilogue, largest grid): ring-3 measured
// +12.3us there; 2-buf syncthreads-drain m97 structure is best.
template<int GELU, int HAS_RES, int OUT_BF16>
__global__ __launch_bounds__(256, 2) void gemm_kernel(
    const u16* __restrict__ A, const u16* __restrict__ Bt,
    const float* __restrict__ bias, const float* __restrict__ res,
    void* __restrict__ Cout, int M, int N, int K)
{
  __shared__ u16 lA[2][128 * 32];
  __shared__ u16 lB[2][128 * 32];
  const int nbn = N >> 7;
  int nwg = gridDim.x;
  int wg = blockIdx.x;
  if ((nwg & 7) == 0) wg = (wg & 7) * (nwg >> 3) + (wg >> 3);
  int bm = wg / nbn, bn = wg % nbn;
  int tid = threadIdx.x;
  int w = tid >> 6, l = tid & 63;
  int lh = l & 15, lg = l >> 4;
  int wr = w >> 1, wc = w & 1;
  const size_t Kb = (size_t)K * 2;
  const char* Ab = (const char*)A + (size_t)(bm * 128) * Kb;
  const char* Bb = (const char*)Bt + (size_t)(bn * 128) * Kb;

  int c0 = w * 64 + l;
  int r0 = c0 >> 2, sw0 = ((c0 ^ (c0 >> 3)) & 3) << 4;
  int c1 = (4 + w) * 64 + l;
  int r1 = c1 >> 2, sw1 = ((c1 ^ (c1 >> 3)) & 3) << 4;

#define GSTAGE(sel, kt)                                                        \
  do {                                                                         \
    GLL16(Ab + (size_t)r0 * Kb + (size_t)(kt) * 64 + sw0,                      \
          (char*)lA[sel] + w * 1024);                                          \
    GLL16(Bb + (size_t)r0 * Kb + (size_t)(kt) * 64 + sw0,                      \
          (char*)lB[sel] + w * 1024);                                          \
    GLL16(Ab + (size_t)r1 * Kb + (size_t)(kt) * 64 + sw1,                      \
          (char*)lA[sel] + (4 + w) * 1024);                                    \
    GLL16(Bb + (size_t)r1 * Kb + (size_t)(kt) * 64 + sw1,                      \
          (char*)lB[sel] + (4 + w) * 1024);                                    \
  } while (0)

  const int swo = ((lg ^ (lh >> 1)) & 3) << 4;
  const int offA = (wr * 64 + lh) * 64 + swo;
  const int offB = (wc * 64 + lh) * 64 + swo;

  f32x4 acc[4][4] = {};
  const int nkt = K >> 5;
  GSTAGE(0, 0);
  __syncthreads();
  int cur = 0;
#pragma unroll 1
  for (int kt = 0; kt < nkt; ++kt) {
    if (kt + 1 < nkt) GSTAGE(cur ^ 1, kt + 1);
    const char* bufA = (const char*)lA[cur];
    const char* bufB = (const char*)lB[cur];
    bf16x8 af[4], bfr[4];
#pragma unroll
    for (int m = 0; m < 4; ++m)
      af[m] = *(const bf16x8*)(bufA + offA + m * 1024);
#pragma unroll
    for (int n = 0; n < 4; ++n)
      bfr[n] = *(const bf16x8*)(bufB + offB + n * 1024);
#pragma unroll
    for (int m = 0; m < 4; ++m)
#pragma unroll
      for (int n = 0; n < 4; ++n)
        acc[m][n] = MFMA16(af[m], bfr[n], acc[m][n]);
    __syncthreads();
    cur ^= 1;
  }
#undef GSTAGE

#pragma unroll
  for (int m = 0; m < 4; ++m) {
    int row0 = bm * 128 + wr * 64 + m * 16 + lg * 4;
#pragma unroll
    for (int n = 0; n < 4; ++n) {
      int col = bn * 128 + wc * 64 + n * 16 + lh;
      float bv = bias[col];
#pragma unroll
      for (int r = 0; r < 4; ++r) {
        int row = row0 + r;
        float v = acc[m][n][r] + bv;
        if (GELU) v = 0.5f * v * (1.0f + erff(v * 0.70710678118f));
        if (HAS_RES) v += res[(size_t)row * N + col];
        if (OUT_BF16) ((u16*)Cout)[(size_t)row * N + col] = f2bf(v);
        else ((float*)Cout)[(size_t)row * N + col] = v;
      }
    }
  }
  (void)M;
}

// --------------------- GEMM 128x128 ring-3 (R5, verified) -------------------
// For QKV, out-proj, FFN2: ring-of-3 buffers, distance-2 prefetch, counted
// s_waitcnt vmcnt(4) + single s_barrier per K-step (no full drain until
// tail). Ledger: R5 vs R7/R11 decomposition shows these three GEMMs are
// faster under ring-3 (combined ~ -24us); only FFN1 regresses.
template<int GELU, int HAS_RES, int OUT_BF16>
__global__ __launch_bounds__(256, 2) void gemm_ring3(
    const u16* __restrict__ A, const u16* __restrict__ Bt,
    const float* __restrict__ bias, const float* __restrict__ res,
    void* __restrict__ Cout, int M, int N, int K)
{
  __shared__ u16 lA[3][128 * 32];
  __shared__ u16 lB[3][128 * 32];
  const int nbn = N >> 7;
  int nwg = gridDim.x;
  int wg = blockIdx.x;
  if ((nwg & 7) == 0) wg = (wg & 7) * (nwg >> 3) + (wg >> 3);
  int bm = wg / nbn, bn = wg % nbn;
  int tid = threadIdx.x;
  int w = tid >> 6, l = tid & 63;
  int lh = l & 15, lg = l >> 4;
  int wr = w >> 1, wc = w & 1;
  const size_t Kb = (size_t)K * 2;
  const char* Ab = (const char*)A + (size_t)(bm * 128) * Kb;
  const char* Bb = (const char*)Bt + (size_t)(bn * 128) * Kb;

  int c0 = w * 64 + l;
  int r0 = c0 >> 2, sw0 = ((c0 ^ (c0 >> 3)) & 3) << 4;
  int c1 = (4 + w) * 64 + l;
  int r1 = c1 >> 2, sw1 = ((c1 ^ (c1 >> 3)) & 3) << 4;

#define GSTAGE(sel, kt)                                                        \
  do {                                                                         \
    GLL16(Ab + (size_t)r0 * Kb + (size_t)(kt) * 64 + sw0,                      \
          (char*)lA[sel] + w * 1024);                                          \
    GLL16(Bb + (size_t)r0 * Kb + (size_t)(kt) * 64 + sw0,                      \
          (char*)lB[sel] + w * 1024);                                          \
    GLL16(Ab + (size_t)r1 * Kb + (size_t)(kt) * 64 + sw1,                      \
          (char*)lA[sel] + (4 + w) * 1024);                                    \
    GLL16(Bb + (size_t)r1 * Kb + (size_t)(kt) * 64 + sw1,                      \
          (char*)lB[sel] + (4 + w) * 1024);                                    \
  } while (0)

  const int swo = ((lg ^ (lh >> 1)) & 3) << 4;
  const int offA = (wr * 64 + lh) * 64 + swo;
  const int offB = (wc * 64 + lh) * 64 + swo;

  f32x4 acc[4][4] = {};
  const int nkt = K >> 5;
  GSTAGE(0, 0);
  GSTAGE(1, 1);
  asm volatile("s_waitcnt vmcnt(4)" ::: "memory");   // tile 0 resident
  __builtin_amdgcn_s_barrier();
  __builtin_amdgcn_sched_barrier(0);

  int cur = 0, s2 = 2;
#pragma unroll 1
  for (int t = 0; t < nkt; ++t) {
    const char* bufA = (const char*)lA[cur];
    const char* bufB = (const char*)lB[cur];
    bf16x8 af[4], bfr[4];
#pragma unroll
    for (int m = 0; m < 4; ++m)
      af[m] = *(const bf16x8*)(bufA + offA + m * 1024);
#pragma unroll
    for (int n = 0; n < 4; ++n)
      bfr[n] = *(const bf16x8*)(bufB + offB + n * 1024);
    if (t + 2 < nkt) GSTAGE(s2, t + 2);   // async, lands 2 steps ahead
    __builtin_amdgcn_s_setprio(1);
#pragma unroll
    for (int m = 0; m < 4; ++m)
#pragma unroll
      for (int n = 0; n < 4; ++n)
        acc[m][n] = MFMA16(af[m], bfr[n], acc[m][n]);
    __builtin_amdgcn_s_setprio(0);
    if (t < nkt - 1) {
      __builtin_amdgcn_sched_barrier(0);
      if (t < nkt - 2) asm volatile("s_waitcnt vmcnt(4)" ::: "memory");
      else             asm volatile("s_waitcnt vmcnt(0)" ::: "memory");
      __builtin_amdgcn_s_barrier();      // tile t+1 resident for all waves
      __builtin_amdgcn_sched_barrier(0);
    }
    cur = (cur == 2) ? 0 : cur + 1;
    s2  = (s2 == 2) ? 0 : s2 + 1;
  }
#undef GSTAGE

#pragma unroll
  for (int m = 0; m < 4; ++m) {
    int row0 = bm * 128 + wr * 64 + m * 16 + lg * 4;
#pragma unroll
    for (int n = 0; n < 4; ++n) {
      int col = bn * 128 + wc * 64 + n * 16 + lh;
      float bv = bias[col];
#pragma unroll
      for (int r = 0; r < 4; ++r) {
        int row = row0 + r;
        float v = acc[m][n][r] + bv;
        if (GELU) v = 0.5f * v * (1.0f + erff(v * 0.70710678118f));
        if (HAS_RES) v += res[(size_t)row * N + col];
        if (OUT_BF16) ((u16*)Cout)[(size_t)row * N + col] = f2bf(v);
        else ((float*)Cout)[(size_t)row * N + col] = v;
      }
    }
  }
  (void)M;
}

// --------------------------- causal flash attention -------------------------
__global__ __launch_bounds__(256, 4) void attn_kernel(
    const u16* __restrict__ qkv, const u16* __restrict__ vt,
    u16* __restrict__ out)
{
  __shared__ u16 Ks[2][4096];
  __shared__ u16 Vs[2][4096];
  __shared__ u16 Ps[4][1024];

  const float C = 0.18033688011f;  // 0.125 * log2(e)

  int bid = blockIdx.x;
  int pi = bid >> 6, bh = bid & 63;
  int b = bh >> 4, h = bh & 15;
  int tid = threadIdx.x;
  int w = tid >> 6, l = tid & 63;
  int lh = l & 15, lg = l >> 4;
  int lh7 = lh & 7;

  const char* kg = (const char*)qkv + (size_t)(b * 2048) * 6144 + 2048 + h * 128;
  const char* vg = (const char*)vt + (size_t)((b * 16 + h) * 64) * 4096;
  char* pbw = (char*)Ps[w] + lh * 128;

#pragma unroll 1
  for (int half = 0; half < 2; ++half) {
    int qb = half ? (31 - pi) : pi;
    int q0 = qb * 64 + w * 16;
    const u16* qbase = qkv + ((size_t)(b * 2048) + q0) * 3072 + h * 64;
    bf16x8 aq0 = *(const bf16x8*)(qbase + (size_t)lh * 3072 + lg * 8);
    bf16x8 aq1 = *(const bf16x8*)(qbase + (size_t)lh * 3072 + 32 + lg * 8);

    f32x4 o[4] = {};
    float m = -1e30f;
    float lsum = 0.f;
    int nt = qb + 1;

    __syncthreads();
#pragma unroll
    for (int i = 0; i < 2; ++i) {
      int u = tid + i * 256;
      int row = u >> 3, uc = u & 7, sw = uc ^ (row & 7);
      GLL16(kg + (size_t)row * 6144 + sw * 16,
            (char*)Ks[0] + (size_t)(i * 256 + w * 64) * 16);
      GLL16(vg + (size_t)row * 4096 + sw * 16,
            (char*)Vs[0] + (size_t)(i * 256 + w * 64) * 16);
    }

#pragma unroll 1
    for (int kt = 0; kt < nt; ++kt) {
      int cur = kt & 1;
      __syncthreads();
      if (kt + 1 < nt) {
        int nxt = cur ^ 1;
        size_t kofs = (size_t)(kt + 1) * 64;
#pragma unroll
        for (int i = 0; i < 2; ++i) {
          int u = tid + i * 256;
          int row = u >> 3, uc = u & 7, sw = uc ^ (row & 7);
          GLL16(kg + (kofs + row) * 6144 + sw * 16,
                (char*)Ks[nxt] + (size_t)(i * 256 + w * 64) * 16);
          GLL16(vg + (size_t)row * 4096 + kofs * 2 + sw * 16,
                (char*)Vs[nxt] + (size_t)(i * 256 + w * 64) * 16);
        }
      }
      const char* kbuf = (const char*)Ks[cur];
      f32x4 s[4];
#pragma unroll
      for (int kb = 0; kb < 4; ++kb) {
        int row = kb * 16 + lh;
        const char* rp = kbuf + row * 128;
        bf16x8 a0 = *(const bf16x8*)(rp + ((lg ^ lh7) << 4));
        bf16x8 a1 = *(const bf16x8*)(rp + (((4 + lg) ^ lh7) << 4));
        f32x4 z = {0.f, 0.f, 0.f, 0.f};
        z = MFMA16(a0, aq0, z);
        z = MFMA16(a1, aq1, z);
        s[kb] = z;
      }
      if (kt == qb) {
        int qin = w * 16 + lh;
#pragma unroll
        for (int kb = 0; kb < 4; ++kb)
#pragma unroll
          for (int r = 0; r < 4; ++r)
            if (kb * 16 + lg * 4 + r > qin) s[kb][r] = -1e30f;
      }
      float tm = fmaxf(fmaxf(s[0][0], s[0][1]), fmaxf(s[0][2], s[0][3]));
#pragma unroll
      for (int kb = 1; kb < 4; ++kb)
        tm = fmaxf(tm, fmaxf(fmaxf(s[kb][0], s[kb][1]), fmaxf(s[kb][2], s[kb][3])));
      tm = fmaxf(tm, __shfl_xor(tm, 16));
      tm = fmaxf(tm, __shfl_xor(tm, 32));
      if (__any(tm > m + 64.0f)) {
        float nm = fmaxf(m, tm);
        float f = __builtin_amdgcn_exp2f((m - nm) * C);
        m = nm; lsum *= f;
#pragma unroll
        for (int db = 0; db < 4; ++db)
#pragma unroll
          for (int r = 0; r < 4; ++r) o[db][r] *= f;
      }
      float mc = m * C;
      float ps = 0.f;
#pragma unroll
      for (int kb = 0; kb < 4; ++kb)
#pragma unroll
        for (int r = 0; r < 4; ++r) {
          float p = __builtin_amdgcn_exp2f(fmaf(s[kb][r], C, -mc));
          s[kb][r] = p;
          ps += p;
        }
      ps += __shfl_xor(ps, 16);
      ps += __shfl_xor(ps, 32);
      lsum += ps;
#pragma unroll
      for (int kb = 0; kb < 4; ++kb) {
        unsigned lo, hi;
        asm("v_cvt_pk_bf16_f32 %0, %1, %2" : "=v"(lo) : "v"(s[kb][0]), "v"(s[kb][1]));
        asm("v_cvt_pk_bf16_f32 %0, %1, %2" : "=v"(hi) : "v"(s[kb][2]), "v"(s[kb][3]));
        int unit = kb * 2 + (lg >> 1);
        uint2 val; val.x = lo; val.y = hi;
        *(uint2*)(pbw + ((unit ^ lh7) << 4) + ((lg & 1) << 3)) = val;
      }
      bf16x8 pa0 = *(const bf16x8*)(pbw + ((lg ^ lh7) << 4));
      bf16x8 pa1 = *(const bf16x8*)(pbw + (((4 + lg) ^ lh7) << 4));
      const char* vbuf = (const char*)Vs[cur];
#pragma unroll
      for (int db = 0; db < 4; ++db) {
        int row = db * 16 + lh;
        const char* rp = vbuf + row * 128;
        bf16x8 v0 = *(const bf16x8*)(rp + ((lg ^ lh7) << 4));
        bf16x8 v1 = *(const bf16x8*)(rp + (((4 + lg) ^ lh7) << 4));
        o[db] = MFMA16(v0, pa0, o[db]);
        o[db] = MFMA16(v1, pa1, o[db]);
      }
    }
    float rinv = 1.0f / lsum;
    u16* ob = out + ((size_t)(b * 2048) + q0 + lh) * 1024 + h * 64;
#pragma unroll
    for (int db = 0; db < 4; ++db) {
      ushort4 pk;
      pk.x = f2bf(o[db][0] * rinv);
      pk.y = f2bf(o[db][1] * rinv);
      pk.z = f2bf(o[db][2] * rinv);
      pk.w = f2bf(o[db][3] * rinv);
      *(ushort4*)(ob + db * 16 + lg * 4) = pk;
    }
  }
}

// ---------------------------------------------------------------------------
extern "C" void kernel_launch(void* const* d_in, const int* in_sizes, int n_in,
                              void* d_out, int out_size, void* d_ws, size_t ws_size,
                              hipStream_t stream) {
  const float* x     = (const float*)d_in[0];
  const float* ln1_g = (const float*)d_in[1];
  const float* ln1_b = (const float*)d_in[2];
  const float* w_qkv = (const float*)d_in[3];
  const float* b_qkv = (const float*)d_in[4];
  const float* w_out = (const float*)d_in[5];
  const float* b_out = (const float*)d_in[6];
  const float* ln2_g = (const float*)d_in[7];
  const float* ln2_b = (const float*)d_in[8];
  const float* w1    = (const float*)d_in[9];
  const float* b1    = (const float*)d_in[10];
  const float* w2    = (const float*)d_in[11];
  const float* b2    = (const float*)d_in[12];

  char* ws = (char*)d_ws;
  // liveness-aliased layout, 142.6 MB total
  u16* wqkvT = (u16*)(ws + 0);          // 6.29 MB
  u16* woutT = (u16*)(ws + 6291456);    // 2.10 MB
  u16* w1T   = (u16*)(ws + 8388608);    // 8.39 MB
  u16* w2T   = (u16*)(ws + 16777216);   // 8.39 MB
  u16* qkv   = (u16*)(ws + 25165824);   // 50.3 MB  [b,l,3,h,d]
  u16* ffn1  = (u16*)(ws + 25165824);   // 67.1 MB  (aliases qkv+vt, both dead)
  u16* vtb   = (u16*)(ws + 75497472);   // 16.8 MB  [b,h,d,l]
  u16* lnb   = (u16*)(ws + 92274688);   // 16.8 MB  (ln1 out / attn out / ln2 out)
  u16* attn  = lnb;
  float* h   = (float*)(ws + 125829120);// 33.6 MB

  wt_kernel<<<dim3(96, 32), 256, 0, stream>>>(w_qkv, wqkvT, 1024, 3072);
  wt_kernel<<<dim3(32, 32), 256, 0, stream>>>(w_out, woutT, 1024, 1024);
  wt_kernel<<<dim3(128, 32), 256, 0, stream>>>(w1, w1T, 1024, 4096);
  wt_kernel<<<dim3(32, 128), 256, 0, stream>>>(w2, w2T, 4096, 1024);

  ln_kernel<<<8192, 256, 0, stream>>>(x, ln1_g, ln1_b, lnb);
  // QKV: K=1024 -> ring-3 (ledger: faster than 2-buf here)
  gemm_ring3<0, 0, 1><<<1536, 256, 0, stream>>>(lnb, wqkvT, b_qkv, nullptr, qkv, 8192, 3072, 1024);
  vt_kernel<<<2048, 256, 0, stream>>>(qkv, vtb);
  attn_kernel<<<1024, 256, 0, stream>>>(qkv, vtb, attn);
  // out-proj: K=1024 -> ring-3
  gemm_ring3<0, 1, 0><<<512, 256, 0, stream>>>(attn, woutT, b_out, x, h, 8192, 1024, 1024);
  ln_kernel<<<8192, 256, 0, stream>>>(h, ln2_g, ln2_b, lnb);
  // FFN1: K=1024, gelu -> 2-buf (ring-3 measured +12.3us here)
  gemm_kernel<1, 0, 1><<<2048, 256, 0, stream>>>(lnb, w1T, b1, nullptr, ffn1, 8192, 4096, 1024);
  // FFN2: K=4096 -> ring-3 counted vmcnt (long K-loop amortizes pipeline)
  gemm_ring3<0, 1, 0><<<512, 256, 0, stream>>>(ffn1, w2T, b2, h, (float*)d_out, 8192, 1024, 4096);
}